// Round 9
// baseline (2642.301 us; speedup 1.0000x reference)
//
#include <hip/hip_runtime.h>
#include <math.h>

#define BB 64
#define TT 32
#define II 512
#define HH 256
#define ZN 1024   // 4*H
#define OO 512
#define NPRE 25

typedef unsigned short u16;
typedef short bfrag __attribute__((ext_vector_type(8)));   // 8 bf16 (4 VGPRs)
typedef float f32x4 __attribute__((ext_vector_type(4)));

__device__ __forceinline__ float sigm_(float x) { return 1.f / (1.f + __expf(-x)); }
__device__ __forceinline__ float tanh_(float x) { return 1.f - 2.f / (__expf(2.f * x) + 1.f); }

__device__ __forceinline__ u16 f2bf(float x) {
    union { float f; unsigned u; } v; v.f = x;
    unsigned r = v.u + 0x7fffu + ((v.u >> 16) & 1u);   // RNE
    return (u16)(r >> 16);
}
__device__ __forceinline__ float bf2f(u16 b) {
    union { unsigned u; float f; } v; v.u = ((unsigned)b) << 16; return v.f;
}

// ---------------------------------------------------------------------------
// Fragment preps: fp32 [D][ld] row-major -> fragment-linear bf16 hi/lo.
//   idx = ((kt*T + t)*64 + l)*8 + i ; d = t*16 + (l&15) ; k = kt*32 + ((l>>4)<<3) + i
// ---------------------------------------------------------------------------
__global__ __launch_bounds__(256) void prep_frag(      // generic (wl)
    const float* __restrict__ src, int ld,
    u16* __restrict__ hi, u16* __restrict__ lo)
{
    const int T  = gridDim.x >> 1;
    const int e2 = blockIdx.x * 256 + threadIdx.x;
    const int kt = blockIdx.y;
    const int i = e2 & 7, l = (e2 >> 3) & 63, t = e2 >> 9;
    const int d = t * 16 + (l & 15);
    const int k = kt * 32 + ((l >> 4) << 3) + i;
    const float v = src[(size_t)d * ld + k];
    const u16 h = f2bf(v);
    const size_t o = (size_t)kt * ((size_t)T * 512) + e2;
    hi[o] = h;
    lo[o] = f2bf(v - bf2f(h));
}

// six [1024][256] matrices fused: whf, whb, w2hf, w2hb, w2if, w2ib
__global__ __launch_bounds__(256) void prep_w8(
    const float* __restrict__ s0, const float* __restrict__ s1,
    const float* __restrict__ s2, const float* __restrict__ s3,
    const float* __restrict__ s4, const float* __restrict__ s5,
    u16* __restrict__ hi, u16* __restrict__ lo)
{
    const int z = blockIdx.z;
    const float* src = (z == 0) ? s0 : (z == 1) ? s1 : (z == 2) ? s2 :
                       (z == 3) ? s3 : (z == 4) ? s4 : s5;
    const int e2 = blockIdx.x * 256 + threadIdx.x;
    const int kt = blockIdx.y;                          // 0..7
    const int i = e2 & 7, l = (e2 >> 3) & 63, t = e2 >> 9;
    const int d = t * 16 + (l & 15);
    const int k = kt * 32 + ((l >> 4) << 3) + i;
    const float v = src[(size_t)d * HH + k];
    const u16 h = f2bf(v);
    const size_t o = (size_t)z * 262144 + (size_t)kt * 32768 + e2;
    hi[o] = h;
    lo[o] = f2bf(v - bf2f(h));
}

// two [1024][512] matrices fused: wif, wib
__global__ __launch_bounds__(256) void prep_w16(
    const float* __restrict__ s0, const float* __restrict__ s1,
    u16* __restrict__ hi, u16* __restrict__ lo)
{
    const int z = blockIdx.z;
    const float* src = z ? s1 : s0;
    const int e2 = blockIdx.x * 256 + threadIdx.x;
    const int kt = blockIdx.y;                          // 0..15
    const int i = e2 & 7, l = (e2 >> 3) & 63, t = e2 >> 9;
    const int d = t * 16 + (l & 15);
    const int k = kt * 32 + ((l >> 4) << 3) + i;
    const float v = src[(size_t)d * II + k];
    const u16 h = f2bf(v);
    const size_t o = (size_t)z * 524288 + (size_t)kt * 32768 + e2;
    hi[o] = h;
    lo[o] = f2bf(v - bf2f(h));
}

// x in t-major A-frag layout: m = t*64 + row. K=512, MT=128, KT=16.
__global__ __launch_bounds__(256) void prep_x_tmajor(
    const float* __restrict__ x, u16* __restrict__ hi, u16* __restrict__ lo)
{
    const int e2 = blockIdx.x * 256 + threadIdx.x;
    const int kt = blockIdx.y;
    const int i = e2 & 7, l = (e2 >> 3) & 63, mt = e2 >> 9;
    const int d = mt * 16 + (l & 15);
    const int t = d >> 6, row = d & 63;
    const int k = kt * 32 + ((l >> 4) << 3) + i;
    const float v = x[((size_t)row * TT + t) * II + k];
    const u16 h = f2bf(v);
    const size_t o = (size_t)kt * 65536 + e2;
    hi[o] = h;
    lo[o] = f2bf(v - bf2f(h));
}

// ---------------------------------------------------------------------------
// Register-fragment MFMA GEMM (bf16 x3 ~= fp32), row-major output (tail proj).
// ---------------------------------------------------------------------------
__global__ __launch_bounds__(256) void gemm_mfma(
    const u16* __restrict__ Ahi, const u16* __restrict__ Alo, const int MT, const int kt0,
    const u16* __restrict__ Bhi, const u16* __restrict__ Blo, const int NT,
    const float* __restrict__ bias,
    float* __restrict__ C, const int ldc, const int KT)
{
    const int tid = threadIdx.x;
    const int w = tid >> 6, l = tid & 63;
    const int mt0 = blockIdx.y * 4;
    const int nt0 = blockIdx.x * 16 + w * 4;

    f32x4 acc[4][4];
    #pragma unroll
    for (int a = 0; a < 4; ++a)
        #pragma unroll
        for (int b = 0; b < 4; ++b) acc[a][b] = (f32x4){0.f, 0.f, 0.f, 0.f};

    bfrag ah0[4], al0[4], bh0[4], bl0[4];
    bfrag ah1[4], al1[4], bh1[4], bl1[4];

#define LOADF(AH, AL, BH, BL, KIDX) do {                                          \
    const int kk_ = (KIDX);                                                      \
    _Pragma("unroll") for (int mt = 0; mt < 4; ++mt) {                            \
        const size_t oa = (((size_t)(kt0 + kk_) * MT + mt0 + mt) * 64 + l) * 8;   \
        AH[mt] = *(const bfrag*)(Ahi + oa); AL[mt] = *(const bfrag*)(Alo + oa); } \
    _Pragma("unroll") for (int j = 0; j < 4; ++j) {                               \
        const size_t ob = (((size_t)kk_ * NT + nt0 + j) * 64 + l) * 8;            \
        BH[j] = *(const bfrag*)(Bhi + ob); BL[j] = *(const bfrag*)(Blo + ob); }   \
} while (0)

#define MFMAS(AH, AL, BH, BL) do {                                                \
    _Pragma("unroll") for (int mt = 0; mt < 4; ++mt)                              \
    _Pragma("unroll") for (int j = 0; j < 4; ++j) {                               \
        acc[mt][j] = __builtin_amdgcn_mfma_f32_16x16x32_bf16(AH[mt], BH[j], acc[mt][j], 0, 0, 0); \
        acc[mt][j] = __builtin_amdgcn_mfma_f32_16x16x32_bf16(AH[mt], BL[j], acc[mt][j], 0, 0, 0); \
        acc[mt][j] = __builtin_amdgcn_mfma_f32_16x16x32_bf16(AL[mt], BH[j], acc[mt][j], 0, 0, 0); } \
} while (0)

    LOADF(ah0, al0, bh0, bl0, 0);
    for (int kt = 0; kt < KT; kt += 2) {
        LOADF(ah1, al1, bh1, bl1, kt + 1);
        MFMAS(ah0, al0, bh0, bl0);
        if (kt + 2 < KT) LOADF(ah0, al0, bh0, bl0, kt + 2);
        MFMAS(ah1, al1, bh1, bl1);
    }

    const int rsub = (l >> 4) << 2;
    #pragma unroll
    for (int j = 0; j < 4; ++j) {
        const int col = (nt0 + j) * 16 + (l & 15);
        const float bv = bias[col];
        #pragma unroll
        for (int mt = 0; mt < 4; ++mt)
            #pragma unroll
            for (int reg = 0; reg < 4; ++reg)
                C[(size_t)((mt0 + mt) * 16 + rsub + reg) * ldc + col] = acc[mt][j][reg] + bv;
    }
#undef LOADF
#undef MFMAS
}

// ---------------------------------------------------------------------------
// xg-producer GEMM, z-fused (proven rounds 5-8).
// Output in MFMA C/D fragment layout: xgP[(((t*64 + nt)*4 + mt)*64 + l)*4 + reg]
// ---------------------------------------------------------------------------
__global__ __launch_bounds__(256) void gemm_xg(
    const u16* __restrict__ Ahi, const u16* __restrict__ Alo, const int kt0h,
    const u16* __restrict__ Bhi0, const u16* __restrict__ Blo0, const size_t bstride,
    const float* __restrict__ bias_even, const float* __restrict__ bias_odd,
    float* __restrict__ out0, const int KT)
{
    const int MT = 128, NT = 64;
    const int z = blockIdx.z;
    const int kt0 = (z >> 1) * kt0h;
    const u16* Bhi = Bhi0 + (size_t)(z & 1) * bstride;
    const u16* Blo = Blo0 + (size_t)(z & 1) * bstride;
    const float* bias = (z & 1) ? bias_odd : bias_even;
    float* out = out0 + (size_t)z * ((size_t)BB * TT * ZN);

    const int tid = threadIdx.x;
    const int w = tid >> 6, l = tid & 63;
    const int t = blockIdx.y;
    const int mt0 = t * 4;
    const int nt0 = blockIdx.x * 16 + w * 4;

    f32x4 acc[4][4];
    #pragma unroll
    for (int a = 0; a < 4; ++a)
        #pragma unroll
        for (int b = 0; b < 4; ++b) acc[a][b] = (f32x4){0.f, 0.f, 0.f, 0.f};

    bfrag ah0[4], al0[4], bh0[4], bl0[4];
    bfrag ah1[4], al1[4], bh1[4], bl1[4];

#define LOADF(AH, AL, BH, BL, KIDX) do {                                          \
    const int kk_ = (KIDX);                                                      \
    _Pragma("unroll") for (int mt = 0; mt < 4; ++mt) {                            \
        const size_t oa = (((size_t)(kt0 + kk_) * MT + mt0 + mt) * 64 + l) * 8;   \
        AH[mt] = *(const bfrag*)(Ahi + oa); AL[mt] = *(const bfrag*)(Alo + oa); } \
    _Pragma("unroll") for (int j = 0; j < 4; ++j) {                               \
        const size_t ob = (((size_t)kk_ * NT + nt0 + j) * 64 + l) * 8;            \
        BH[j] = *(const bfrag*)(Bhi + ob); BL[j] = *(const bfrag*)(Blo + ob); }   \
} while (0)

#define MFMAS(AH, AL, BH, BL) do {                                                \
    _Pragma("unroll") for (int mt = 0; mt < 4; ++mt)                              \
    _Pragma("unroll") for (int j = 0; j < 4; ++j) {                               \
        acc[mt][j] = __builtin_amdgcn_mfma_f32_16x16x32_bf16(AH[mt], BH[j], acc[mt][j], 0, 0, 0); \
        acc[mt][j] = __builtin_amdgcn_mfma_f32_16x16x32_bf16(AH[mt], BL[j], acc[mt][j], 0, 0, 0); \
        acc[mt][j] = __builtin_amdgcn_mfma_f32_16x16x32_bf16(AL[mt], BH[j], acc[mt][j], 0, 0, 0); } \
} while (0)

    LOADF(ah0, al0, bh0, bl0, 0);
    for (int kt = 0; kt < KT; kt += 2) {
        LOADF(ah1, al1, bh1, bl1, kt + 1);
        MFMAS(ah0, al0, bh0, bl0);
        if (kt + 2 < KT) LOADF(ah0, al0, bh0, bl0, kt + 2);
        MFMAS(ah1, al1, bh1, bl1);
    }
#undef LOADF
#undef MFMAS

    const int cl = l & 15;
    #pragma unroll
    for (int j = 0; j < 4; ++j) {
        const float bv = bias[(nt0 + j) * 16 + cl];
        #pragma unroll
        for (int mt = 0; mt < 4; ++mt) {
            f32x4 o = acc[mt][j];
            o[0] += bv; o[1] += bv; o[2] += bv; o[3] += bv;
            *(f32x4*)(out + ((((size_t)t * 64 + nt0 + j) * 4 + mt) * 64 + l) * 4) = o;
        }
    }
}

// ---------------------------------------------------------------------------
// Recurrence, ROW-PARTITIONED: 112 fully independent WGs = 56 runs x 2 row
// halves (32 batch rows each). LSTM batch rows are independent, so h lives in
// LDS for the whole run -- NO cross-WG exchange, NO atomics, NO coop launch
// (round 6-8 lesson: per-step device-coherent handoff costs ~15us/step fixed).
// Weights are STREAMED from L2 each step (1 MB/WG/step, hi+lo), pipelined in
// half-kt-slab register double-buffers overlapping the MFMAs.
// Wave w owns h-col tiles c = 4*c4 + w (c4=0..3) x 4 gates -> each thread has
// all 4 gate values for its h-columns. acc[mt][c4][g], c/mx[mt][c4][reg].
// h LDS A-frag: idx = ((kt*2 + mt)*64 + lane)*8 + i ; local row d = mt*16+(lane&15),
// k = kt*32 + (lane>>4)*8 + i.
// run ids: 0 L1 fwd full | 1 L1 bwd full | 2..26 bwd prefix len 1..25 |
//          27..51 fwd suffix len 1..25 | 52..55 L2 (r2f,r2b,r3f,r3b)
// ---------------------------------------------------------------------------
__global__ __launch_bounds__(256, 1) void lstm_rows(
    const float* __restrict__ xgfP, const float* __restrict__ xgbP,
    const float* __restrict__ xg2P,
    const u16* __restrict__ Whi, const u16* __restrict__ Wlo,
    float* __restrict__ out_pre, float* __restrict__ out_suf,
    u16* __restrict__ r4Ah, u16* __restrict__ r4Al)
{
    __shared__ u16 hh[8192];   // 16 KB: h hi, A-frag layout (32 rows x 256 k)
    __shared__ u16 hl[8192];   // 16 KB: h lo

    const int wg  = blockIdx.x;
    const int rid = wg >> 1;
    const int r   = wg & 1;          // row half: rows r*32 .. r*32+31
    const int tid = threadIdx.x;
    const int w   = tid >> 6;
    const int l   = tid & 63;

    const float* xg; int wmat, t0, dt, ns, mode, len = 0, part = 0;
    if (rid == 0)      { mode = 0; ns = 32; t0 = 0;  dt = 1;  xg = xgfP; wmat = 0; }
    else if (rid == 1) { mode = 1; ns = 32; t0 = 31; dt = -1; xg = xgbP; wmat = 1; }
    else if (rid < 27) { mode = 2; len = rid - 1;  ns = len;      t0 = len - 1; dt = -1; xg = xgbP; wmat = 1; }
    else if (rid < 52) { mode = 3; len = rid - 26; ns = 32 - len; t0 = len;     dt = 1;  xg = xgfP; wmat = 0; }
    else { mode = 4; part = rid - 52; ns = 32;
           xg = xg2P + (size_t)part * ((size_t)BB * TT * ZN);
           wmat = 2 + (part & 1); if (part & 1) { t0 = 31; dt = -1; } else { t0 = 0; dt = 1; } }

    const u16* WHp = Whi + (size_t)wmat * 262144;
    const u16* WLp = Wlo + (size_t)wmat * 262144;

    const int cl = l & 15, rsub = (l >> 4) << 2;
    const int mtg0 = r * 2;                      // global mt base for xg reads

    float c[2][4][4], mx[2][4][4];               // [mt][c4][reg]
    #pragma unroll
    for (int a = 0; a < 2; ++a)
        #pragma unroll
        for (int b = 0; b < 4; ++b)
            #pragma unroll
            for (int e = 0; e < 4; ++e) { c[a][b][e] = 0.f; mx[a][b][e] = -3.4e38f; }

#define ALOAD(AH, AL, KT_) do {                                                   \
    _Pragma("unroll") for (int mt_ = 0; mt_ < 2; ++mt_) {                         \
        const int oa_ = (((KT_) * 2 + mt_) * 64 + l) * 8;                         \
        AH[mt_] = *(const bfrag*)&hh[oa_];                                        \
        AL[mt_] = *(const bfrag*)&hl[oa_]; }                                      \
} while (0)

#define WLOADH(BH, BL, KT_, HF_) do {                                             \
    _Pragma("unroll") for (int j_ = 0; j_ < 8; ++j_) {                            \
        const int nt_ = ((HF_) * 2 + (j_ >> 2)) * 16 + (j_ & 3) * 4 + w;          \
        const size_t ob_ = (((size_t)(KT_) * 64 + nt_) * 64 + l) * 8;             \
        BH[j_] = *(const bfrag*)(WHp + ob_);                                      \
        BL[j_] = *(const bfrag*)(WLp + ob_); }                                    \
} while (0)

#define WMFMAH(AH, AL, BH, BL, HF_) do {                                          \
    _Pragma("unroll") for (int mt_ = 0; mt_ < 2; ++mt_)                           \
    _Pragma("unroll") for (int j_ = 0; j_ < 8; ++j_) {                            \
        const int g_ = (HF_) * 2 + (j_ >> 2), c4_ = j_ & 3;                       \
        acc[mt_][c4_][g_] = __builtin_amdgcn_mfma_f32_16x16x32_bf16(AH[mt_], BH[j_], acc[mt_][c4_][g_], 0, 0, 0); \
        acc[mt_][c4_][g_] = __builtin_amdgcn_mfma_f32_16x16x32_bf16(AH[mt_], BL[j_], acc[mt_][c4_][g_], 0, 0, 0); \
        acc[mt_][c4_][g_] = __builtin_amdgcn_mfma_f32_16x16x32_bf16(AL[mt_], BH[j_], acc[mt_][c4_][g_], 0, 0, 0); } \
} while (0)

#define KTBLK(AH, AL, ANH, ANL, KT_) do {                                         \
    WLOADH(bBh, bBl, KT_, 1);                                                     \
    WMFMAH(AH, AL, bAh, bAl, 0);                                                  \
    if ((KT_) < 7) WLOADH(bAh, bAl, (KT_) + 1, 0);                                \
    WMFMAH(AH, AL, bBh, bBl, 1);                                                  \
    if ((KT_) < 7) ALOAD(ANH, ANL, (KT_) + 1);                                    \
} while (0)

    for (int s = 0; s < ns; ++s) {
        const int t = t0 + dt * s;

        f32x4 acc[2][4][4];                      // [mt][c4][g]
        #pragma unroll
        for (int a = 0; a < 2; ++a)
            #pragma unroll
            for (int b = 0; b < 4; ++b)
                #pragma unroll
                for (int g = 0; g < 4; ++g) acc[a][b][g] = (f32x4){0.f, 0.f, 0.f, 0.f};

        if (s > 0) {
            // z += h @ W^T : LDS a-frags, weights streamed hi/lo, pipelined
            bfrag a0h[2], a0l[2], a1h[2], a1l[2];
            bfrag bAh[8], bAl[8], bBh[8], bBl[8];
            ALOAD(a0h, a0l, 0);
            WLOADH(bAh, bAl, 0, 0);
            KTBLK(a0h, a0l, a1h, a1l, 0);
            KTBLK(a1h, a1l, a0h, a0l, 1);
            KTBLK(a0h, a0l, a1h, a1l, 2);
            KTBLK(a1h, a1l, a0h, a0l, 3);
            KTBLK(a0h, a0l, a1h, a1l, 4);
            KTBLK(a1h, a1l, a0h, a0l, 5);
            KTBLK(a0h, a0l, a1h, a1l, 6);
            KTBLK(a1h, a1l, a0h, a0l, 7);
        }
        __syncthreads();   // h LDS reads complete before epilogue overwrites

        // ------------------ gates + state update + outputs ------------------
        #pragma unroll
        for (int mt = 0; mt < 2; ++mt) {
            #pragma unroll
            for (int c4 = 0; c4 < 4; ++c4) {
                f32x4 xv[4];
                #pragma unroll
                for (int g = 0; g < 4; ++g) {
                    const int nt = g * 16 + c4 * 4 + w;
                    xv[g] = *(const f32x4*)(xg +
                        ((((size_t)t * 64 + nt) * 4 + mtg0 + mt) * 64 + l) * 4);
                }
                const int hc  = (c4 * 4 + w) * 16 + cl;
                const int ktp = hc >> 5, lq = (hc >> 3) & 3, i2 = hc & 7;
                const int kk4 = part * 256 + hc;
                const int ktp4 = kk4 >> 5, lph = ((kk4 >> 3) & 3) * 16, ip = kk4 & 7;
                #pragma unroll
                for (int reg = 0; reg < 4; ++reg) {
                    const int rowl = mt * 16 + rsub + reg;       // local row 0..31
                    const int row  = r * 32 + rowl;              // global batch row
                    const float zi = acc[mt][c4][0][reg] + xv[0][reg];
                    const float zf = acc[mt][c4][1][reg] + xv[1][reg];
                    const float zg = acc[mt][c4][2][reg] + xv[2][reg];
                    const float zo = acc[mt][c4][3][reg] + xv[3][reg];
                    const float c2 = sigm_(zf) * c[mt][c4][reg] + sigm_(zi) * tanh_(zg);
                    const float h2 = sigm_(zo) * tanh_(c2);
                    c[mt][c4][reg] = c2;
                    const float m2 = fmaxf(mx[mt][c4][reg], h2);
                    mx[mt][c4][reg] = m2;

                    const u16 uh = f2bf(h2);
                    const u16 ul = f2bf(h2 - bf2f(uh));

                    // h -> LDS A-frag for next step (local rows)
                    const int hidx = ((ktp * 2 + mt) * 64 + (rsub + reg) + 16 * lq) * 8 + i2;
                    hh[hidx] = uh;
                    hl[hidx] = ul;

                    if (mode == 0) {
                        if (t <= 24)
                            out_pre[((size_t)t * BB + row) * (2 * HH) + hc] = m2;
                    } else if (mode == 1) {
                        if (t >= 1 && t <= 25)
                            out_suf[((size_t)(t - 1) * BB + row) * (2 * HH) + HH + hc] = m2;
                    } else if (mode == 2) {
                        if (s == ns - 1)
                            out_pre[((size_t)(len - 1) * BB + row) * (2 * HH) + HH + hc] = m2;
                    } else if (mode == 3) {
                        if (s == ns - 1)
                            out_suf[((size_t)(len - 1) * BB + row) * (2 * HH) + hc] = m2;
                    } else {
                        // r4 directly in proj-A fragment layout: d = row*32+t
                        const int d = row * 32 + t;
                        const size_t idx = (((size_t)ktp4 * 128 + (d >> 4)) * 64
                                            + lph + (d & 15)) * 8 + ip;
                        r4Ah[idx] = uh;
                        r4Al[idx] = ul;
                    }
                }
            }
        }
        __syncthreads();   // h LDS writes visible for next step's a-frag reads
    }
#undef ALOAD
#undef WLOADH
#undef WMFMAH
#undef KTBLK
}

// ---------------------------------------------------------------------------
extern "C" void kernel_launch(void* const* d_in, const int* in_sizes, int n_in,
                              void* d_out, int out_size, void* d_ws, size_t ws_size,
                              hipStream_t stream)
{
    const float* x    = (const float*)d_in[0];
    const float* wif  = (const float*)d_in[1];
    const float* whf  = (const float*)d_in[2];
    const float* bf   = (const float*)d_in[3];
    const float* wib  = (const float*)d_in[4];
    const float* whb  = (const float*)d_in[5];
    const float* bb   = (const float*)d_in[6];
    const float* w2if = (const float*)d_in[7];
    const float* w2hf = (const float*)d_in[8];
    const float* b2f  = (const float*)d_in[9];
    const float* w2ib = (const float*)d_in[10];
    const float* w2hb = (const float*)d_in[11];
    const float* b2b  = (const float*)d_in[12];
    const float* wl   = (const float*)d_in[13];
    const float* bl   = (const float*)d_in[14];

    const size_t XG = (size_t)BB * TT * ZN;          // 2,097,152 floats
    float* xgfP  = (float*)d_ws;
    float* xgbP  = xgfP + XG;
    float* xg2P  = xgbP + XG;                        // 4 consecutive arrays

    u16* p = (u16*)(xg2P + 4 * XG);
    u16* WB8h  = p; p += (size_t)6 * 262144;   // whf,whb,w2hf,w2hb,w2if,w2ib
    u16* WB8l  = p; p += (size_t)6 * 262144;
    u16* WB16h = p; p += (size_t)2 * 524288;   // wif, wib
    u16* WB16l = p; p += (size_t)2 * 524288;
    u16* wlBh  = p; p += (size_t)524288;
    u16* wlBl  = p; p += (size_t)524288;
    u16* xAh   = p; p += (size_t)2048 * 512;
    u16* xAl   = p; p += (size_t)2048 * 512;
    u16* r4Ah  = p; p += (size_t)2048 * 1024;
    u16* r4Al  = p; p += (size_t)2048 * 1024;

    float* outp    = (float*)d_out;
    float* out_pre = outp + (size_t)BB * TT * OO;
    float* out_suf = out_pre + (size_t)NPRE * BB * (2 * HH);

    // 1. fragment preps (fused)
    prep_w8 <<<dim3(128, 8, 6),  256, 0, stream>>>(whf, whb, w2hf, w2hb, w2if, w2ib, WB8h, WB8l);
    prep_w16<<<dim3(128, 16, 2), 256, 0, stream>>>(wif, wib, WB16h, WB16l);
    prep_frag<<<dim3(64, 32),    256, 0, stream>>>(wl, ZN, wlBh, wlBl);      // T=32, K=1024
    prep_x_tmajor<<<dim3(256, 16), 256, 0, stream>>>(x, xAh, xAl);

    // 2. input-gate activation GEMMs -> fragment-layout xgP buffers (fused)
    gemm_xg<<<dim3(4, 32, 2), 256, 0, stream>>>(xAh, xAl, 0, WB16h, WB16l, 524288,
                                                bf, bb, xgfP, 16);
    gemm_xg<<<dim3(4, 32, 4), 256, 0, stream>>>(xAh, xAl, 8,
                                                WB8h + (size_t)4 * 262144, WB8l + (size_t)4 * 262144, 262144,
                                                b2f, b2b, xg2P, 8);

    // 3. recurrence: 112 fully independent row-partitioned WGs, plain launch
    lstm_rows<<<dim3(112), dim3(256), 0, stream>>>(xgfP, xgbP, xg2P,
                                                   WB8h, WB8l,
                                                   out_pre, out_suf, r4Ah, r4Al);

    // 4. final projection: output = r4 @ wl^T + bl  (r4 already in frag layout)
    gemm_mfma<<<dim3(2, 32), 256, 0, stream>>>(r4Ah, r4Al, 128, 0, wlBh, wlBl, 32, bl, outp, OO, 32);
}

// Round 10
// 638.728 us; speedup vs baseline: 4.1368x; 4.1368x over previous
//
#include <hip/hip_runtime.h>
#include <math.h>

#define BB 64
#define TT 32
#define II 512
#define HH 256
#define ZN 1024   // 4*H
#define OO 512
#define NPRE 25

typedef unsigned short u16;
typedef unsigned long long u64;
typedef short bfrag __attribute__((ext_vector_type(8)));      // 8 bf16 (4 VGPRs)
typedef _Float16 hfrag __attribute__((ext_vector_type(8)));   // 8 f16  (4 VGPRs)
typedef float f32x4 __attribute__((ext_vector_type(4)));

__device__ __forceinline__ float sigm_(float x) { return 1.f / (1.f + __expf(-x)); }
__device__ __forceinline__ float tanh_(float x) { return 1.f - 2.f / (__expf(2.f * x) + 1.f); }

__device__ __forceinline__ u16 f2bf(float x) {
    union { float f; unsigned u; } v; v.f = x;
    unsigned r = v.u + 0x7fffu + ((v.u >> 16) & 1u);   // RNE
    return (u16)(r >> 16);
}
__device__ __forceinline__ float bf2f(u16 b) {
    union { unsigned u; float f; } v; v.u = ((unsigned)b) << 16; return v.f;
}
__device__ __forceinline__ u16 f2h_bits(float x) {
    union { _Float16 h; u16 u; } v; v.h = (_Float16)x; return v.u;
}

// ---------------------------------------------------------------------------
// Fragment preps: fp32 [D][ld] row-major -> fragment-linear.
//   frag idx = ((kt*T + t)*64 + l)*8 + i ; d = t*16+(l&15) ; k = kt*32+((l>>4)<<3)+i
// ---------------------------------------------------------------------------
__global__ __launch_bounds__(256) void prep_frag(      // bf16 hi/lo (wl)
    const float* __restrict__ src, int ld,
    u16* __restrict__ hi, u16* __restrict__ lo)
{
    const int T  = gridDim.x >> 1;
    const int e2 = blockIdx.x * 256 + threadIdx.x;
    const int kt = blockIdx.y;
    const int i = e2 & 7, l = (e2 >> 3) & 63, t = e2 >> 9;
    const int d = t * 16 + (l & 15);
    const int k = kt * 32 + ((l >> 4) << 3) + i;
    const float v = src[(size_t)d * ld + k];
    const u16 h = f2bf(v);
    const size_t o = (size_t)kt * ((size_t)T * 512) + e2;
    hi[o] = h;
    lo[o] = f2bf(v - bf2f(h));
}

// 4 recurrence matrices [1024][256] -> f16 frag-linear (x1 scheme)
__global__ __launch_bounds__(256) void prep_w4h(
    const float* __restrict__ s0, const float* __restrict__ s1,
    const float* __restrict__ s2, const float* __restrict__ s3,
    _Float16* __restrict__ dst)
{
    const int z = blockIdx.z;
    const float* src = (z == 0) ? s0 : (z == 1) ? s1 : (z == 2) ? s2 : s3;
    const int e2 = blockIdx.x * 256 + threadIdx.x;
    const int kt = blockIdx.y;                          // 0..7
    const int i = e2 & 7, l = (e2 >> 3) & 63, t = e2 >> 9;
    const int d = t * 16 + (l & 15);
    const int k = kt * 32 + ((l >> 4) << 3) + i;
    dst[(size_t)z * 262144 + (size_t)kt * 32768 + e2] =
        (_Float16)src[(size_t)d * HH + k];
}

// 2 matrices [1024][256] bf16 hi/lo: w2if, w2ib (xg-GEMM B operands)
__global__ __launch_bounds__(256) void prep_w2(
    const float* __restrict__ s0, const float* __restrict__ s1,
    u16* __restrict__ hi, u16* __restrict__ lo)
{
    const int z = blockIdx.z;
    const float* src = z ? s1 : s0;
    const int e2 = blockIdx.x * 256 + threadIdx.x;
    const int kt = blockIdx.y;                          // 0..7
    const int i = e2 & 7, l = (e2 >> 3) & 63, t = e2 >> 9;
    const int d = t * 16 + (l & 15);
    const int k = kt * 32 + ((l >> 4) << 3) + i;
    const float v = src[(size_t)d * HH + k];
    const u16 h = f2bf(v);
    const size_t o = (size_t)z * 262144 + (size_t)kt * 32768 + e2;
    hi[o] = h;
    lo[o] = f2bf(v - bf2f(h));
}

// two [1024][512] matrices fused: wif, wib
__global__ __launch_bounds__(256) void prep_w16(
    const float* __restrict__ s0, const float* __restrict__ s1,
    u16* __restrict__ hi, u16* __restrict__ lo)
{
    const int z = blockIdx.z;
    const float* src = z ? s1 : s0;
    const int e2 = blockIdx.x * 256 + threadIdx.x;
    const int kt = blockIdx.y;                          // 0..15
    const int i = e2 & 7, l = (e2 >> 3) & 63, t = e2 >> 9;
    const int d = t * 16 + (l & 15);
    const int k = kt * 32 + ((l >> 4) << 3) + i;
    const float v = src[(size_t)d * II + k];
    const u16 h = f2bf(v);
    const size_t o = (size_t)z * 524288 + (size_t)kt * 32768 + e2;
    hi[o] = h;
    lo[o] = f2bf(v - bf2f(h));
}

// x in t-major A-frag layout: m = t*64 + row. K=512, MT=128, KT=16.
__global__ __launch_bounds__(256) void prep_x_tmajor(
    const float* __restrict__ x, u16* __restrict__ hi, u16* __restrict__ lo)
{
    const int e2 = blockIdx.x * 256 + threadIdx.x;
    const int kt = blockIdx.y;
    const int i = e2 & 7, l = (e2 >> 3) & 63, mt = e2 >> 9;
    const int d = mt * 16 + (l & 15);
    const int t = d >> 6, row = d & 63;
    const int k = kt * 32 + ((l >> 4) << 3) + i;
    const float v = x[((size_t)row * TT + t) * II + k];
    const u16 h = f2bf(v);
    const size_t o = (size_t)kt * 65536 + e2;
    hi[o] = h;
    lo[o] = f2bf(v - bf2f(h));
}

// ---------------------------------------------------------------------------
// Register-fragment MFMA GEMM (bf16 x3 ~= fp32), row-major output (tail proj).
// ---------------------------------------------------------------------------
__global__ __launch_bounds__(256) void gemm_mfma(
    const u16* __restrict__ Ahi, const u16* __restrict__ Alo, const int MT, const int kt0,
    const u16* __restrict__ Bhi, const u16* __restrict__ Blo, const int NT,
    const float* __restrict__ bias,
    float* __restrict__ C, const int ldc, const int KT)
{
    const int tid = threadIdx.x;
    const int w = tid >> 6, l = tid & 63;
    const int mt0 = blockIdx.y * 4;
    const int nt0 = blockIdx.x * 16 + w * 4;

    f32x4 acc[4][4];
    #pragma unroll
    for (int a = 0; a < 4; ++a)
        #pragma unroll
        for (int b = 0; b < 4; ++b) acc[a][b] = (f32x4){0.f, 0.f, 0.f, 0.f};

    bfrag ah0[4], al0[4], bh0[4], bl0[4];
    bfrag ah1[4], al1[4], bh1[4], bl1[4];

#define LOADF(AH, AL, BH, BL, KIDX) do {                                          \
    const int kk_ = (KIDX);                                                      \
    _Pragma("unroll") for (int mt = 0; mt < 4; ++mt) {                            \
        const size_t oa = (((size_t)(kt0 + kk_) * MT + mt0 + mt) * 64 + l) * 8;   \
        AH[mt] = *(const bfrag*)(Ahi + oa); AL[mt] = *(const bfrag*)(Alo + oa); } \
    _Pragma("unroll") for (int j = 0; j < 4; ++j) {                               \
        const size_t ob = (((size_t)kk_ * NT + nt0 + j) * 64 + l) * 8;            \
        BH[j] = *(const bfrag*)(Bhi + ob); BL[j] = *(const bfrag*)(Blo + ob); }   \
} while (0)

#define MFMAS(AH, AL, BH, BL) do {                                                \
    _Pragma("unroll") for (int mt = 0; mt < 4; ++mt)                              \
    _Pragma("unroll") for (int j = 0; j < 4; ++j) {                               \
        acc[mt][j] = __builtin_amdgcn_mfma_f32_16x16x32_bf16(AH[mt], BH[j], acc[mt][j], 0, 0, 0); \
        acc[mt][j] = __builtin_amdgcn_mfma_f32_16x16x32_bf16(AH[mt], BL[j], acc[mt][j], 0, 0, 0); \
        acc[mt][j] = __builtin_amdgcn_mfma_f32_16x16x32_bf16(AL[mt], BH[j], acc[mt][j], 0, 0, 0); } \
} while (0)

    LOADF(ah0, al0, bh0, bl0, 0);
    for (int kt = 0; kt < KT; kt += 2) {
        LOADF(ah1, al1, bh1, bl1, kt + 1);
        MFMAS(ah0, al0, bh0, bl0);
        if (kt + 2 < KT) LOADF(ah0, al0, bh0, bl0, kt + 2);
        MFMAS(ah1, al1, bh1, bl1);
    }

    const int rsub = (l >> 4) << 2;
    #pragma unroll
    for (int j = 0; j < 4; ++j) {
        const int col = (nt0 + j) * 16 + (l & 15);
        const float bv = bias[col];
        #pragma unroll
        for (int mt = 0; mt < 4; ++mt)
            #pragma unroll
            for (int reg = 0; reg < 4; ++reg)
                C[(size_t)((mt0 + mt) * 16 + rsub + reg) * ldc + col] = acc[mt][j][reg] + bv;
    }
#undef LOADF
#undef MFMAS
}

// ---------------------------------------------------------------------------
// xg-producer GEMM, z-fused (proven rounds 5-8).
// Output in MFMA C/D fragment layout: xgP[(((t*64 + nt)*4 + mt)*64 + l)*4 + reg]
// ---------------------------------------------------------------------------
__global__ __launch_bounds__(256) void gemm_xg(
    const u16* __restrict__ Ahi, const u16* __restrict__ Alo, const int kt0h,
    const u16* __restrict__ Bhi0, const u16* __restrict__ Blo0, const size_t bstride,
    const float* __restrict__ bias_even, const float* __restrict__ bias_odd,
    float* __restrict__ out0, const int KT)
{
    const int MT = 128, NT = 64;
    const int z = blockIdx.z;
    const int kt0 = (z >> 1) * kt0h;
    const u16* Bhi = Bhi0 + (size_t)(z & 1) * bstride;
    const u16* Blo = Blo0 + (size_t)(z & 1) * bstride;
    const float* bias = (z & 1) ? bias_odd : bias_even;
    float* out = out0 + (size_t)z * ((size_t)BB * TT * ZN);

    const int tid = threadIdx.x;
    const int w = tid >> 6, l = tid & 63;
    const int t = blockIdx.y;
    const int mt0 = t * 4;
    const int nt0 = blockIdx.x * 16 + w * 4;

    f32x4 acc[4][4];
    #pragma unroll
    for (int a = 0; a < 4; ++a)
        #pragma unroll
        for (int b = 0; b < 4; ++b) acc[a][b] = (f32x4){0.f, 0.f, 0.f, 0.f};

    bfrag ah0[4], al0[4], bh0[4], bl0[4];
    bfrag ah1[4], al1[4], bh1[4], bl1[4];

#define LOADF(AH, AL, BH, BL, KIDX) do {                                          \
    const int kk_ = (KIDX);                                                      \
    _Pragma("unroll") for (int mt = 0; mt < 4; ++mt) {                            \
        const size_t oa = (((size_t)(kt0 + kk_) * MT + mt0 + mt) * 64 + l) * 8;   \
        AH[mt] = *(const bfrag*)(Ahi + oa); AL[mt] = *(const bfrag*)(Alo + oa); } \
    _Pragma("unroll") for (int j = 0; j < 4; ++j) {                               \
        const size_t ob = (((size_t)kk_ * NT + nt0 + j) * 64 + l) * 8;            \
        BH[j] = *(const bfrag*)(Bhi + ob); BL[j] = *(const bfrag*)(Blo + ob); }   \
} while (0)

#define MFMAS(AH, AL, BH, BL) do {                                                \
    _Pragma("unroll") for (int mt = 0; mt < 4; ++mt)                              \
    _Pragma("unroll") for (int j = 0; j < 4; ++j) {                               \
        acc[mt][j] = __builtin_amdgcn_mfma_f32_16x16x32_bf16(AH[mt], BH[j], acc[mt][j], 0, 0, 0); \
        acc[mt][j] = __builtin_amdgcn_mfma_f32_16x16x32_bf16(AH[mt], BL[j], acc[mt][j], 0, 0, 0); \
        acc[mt][j] = __builtin_amdgcn_mfma_f32_16x16x32_bf16(AL[mt], BH[j], acc[mt][j], 0, 0, 0); } \
} while (0)

    LOADF(ah0, al0, bh0, bl0, 0);
    for (int kt = 0; kt < KT; kt += 2) {
        LOADF(ah1, al1, bh1, bl1, kt + 1);
        MFMAS(ah0, al0, bh0, bl0);
        if (kt + 2 < KT) LOADF(ah0, al0, bh0, bl0, kt + 2);
        MFMAS(ah1, al1, bh1, bl1);
    }
#undef LOADF
#undef MFMAS

    const int cl = l & 15;
    #pragma unroll
    for (int j = 0; j < 4; ++j) {
        const float bv = bias[(nt0 + j) * 16 + cl];
        #pragma unroll
        for (int mt = 0; mt < 4; ++mt) {
            f32x4 o = acc[mt][j];
            o[0] += bv; o[1] += bv; o[2] += bv; o[3] += bv;
            *(f32x4*)(out + ((((size_t)t * 64 + nt0 + j) * 4 + mt) * 64 + l) * 4) = o;
        }
    }
}

// ---------------------------------------------------------------------------
// Recurrence (round-8 structure, f16-x1 math). coop: ONE cooperative launch;
// per-run 4-WG barrier; h transport = u64 (4 packed f16) relaxed AGENT
// atomics. Changes vs round 8: f16 weights in 128 VGPR (no spill), MFMA /3,
// exchange bytes /2, LDS 64KB (2 WG/CU), relaxed spin + single acquire,
// nontemporal epilogue stores (keep L2 clean for the release writeback),
// bid = q*56 + rid so a run's 4 WGs likely share an XCD (56%8==0).
// h u64 slot (4096/run): idx = q*1024 + mt*256 + tid; payload = 4 regs f16.
// run ids: 0 L1 fwd full | 1 L1 bwd full | 2..26 bwd prefix len 1..25 |
//          27..51 fwd suffix len 1..25 | 52..55 L2 (r2f,r2b,r3f,r3b)
// ---------------------------------------------------------------------------
__global__ __launch_bounds__(256, 2) void lstm_runs_k(
    const int s0, const int s1,
    const float* __restrict__ xgfP, const float* __restrict__ xgbP,
    const float* __restrict__ xg2P,
    const _Float16* __restrict__ W16,
    u64* __restrict__ hU, unsigned* __restrict__ bar,
    float* __restrict__ c_st, float* __restrict__ mx_st,
    float* __restrict__ out_pre, float* __restrict__ out_suf,
    u16* __restrict__ r4Ah, u16* __restrict__ r4Al)
{
    __shared__ u16 hh[2][16384];   // 64 KB: h f16 bits, A-frag-linear, dbuf

    const int wg  = blockIdx.x;
    const int rid = wg % 56;       // co-XCD mapping: wg = q*56 + rid
    const int q   = wg / 56;
    const int tid = threadIdx.x;
    const int w   = tid >> 6;
    const int l   = tid & 63;
    const bool coop = (s1 - s0) > 1;

    const float* xg; int wmat, t0, dt, ns, mode, len = 0, part = 0;
    if (rid == 0)      { mode = 0; ns = 32; t0 = 0;  dt = 1;  xg = xgfP; wmat = 0; }
    else if (rid == 1) { mode = 1; ns = 32; t0 = 31; dt = -1; xg = xgbP; wmat = 1; }
    else if (rid < 27) { mode = 2; len = rid - 1;  ns = len;      t0 = len - 1; dt = -1; xg = xgbP; wmat = 1; }
    else if (rid < 52) { mode = 3; len = rid - 26; ns = 32 - len; t0 = len;     dt = 1;  xg = xgfP; wmat = 0; }
    else { mode = 4; part = rid - 52; ns = 32;
           xg = xg2P + (size_t)part * ((size_t)BB * TT * ZN);
           wmat = 2 + (part & 1); if (part & 1) { t0 = 31; dt = -1; } else { t0 = 0; dt = 1; } }

    if (!coop && s0 >= ns) return;

    // ---- weights -> registers (once per launch): 32 frags = 128 VGPR ----
    hfrag WH[8][4];
    {
        const _Float16* WHp = W16 + (size_t)wmat * 262144;
        #pragma unroll
        for (int kt = 0; kt < 8; ++kt)
            #pragma unroll
            for (int g = 0; g < 4; ++g) {
                const size_t ob = (((size_t)kt * 64 + g * 16 + q * 4 + w) * 64 + l) * 8;
                WH[kt][g] = *(const hfrag*)(WHp + ob);
            }
    }

    const int cl = l & 15, rsub = (l >> 4) << 2;
    const int hc = q * 64 + w * 16 + cl;                   // owned h column
    const int kt2 = hc >> 5, i2 = hc & 7, lhi = (hc >> 3) & 3;
    const size_t stBase = ((size_t)wg * 256 + tid) * 16;   // c/mx slot (fallback)
    // mode-4 r4 A-frag lane constants: k = part*256 + hc
    const int kk4 = part * 256 + hc;
    const int ktp4 = kk4 >> 5, lph = ((kk4 >> 3) & 3) * 16, ip = kk4 & 7;
    // reader decode constants (reader tid mirrors writer lane tid)
    const int rw = tid >> 6, rcl = tid & 15, rsw = ((tid >> 4) & 3) << 2;

    float c[4][4], mx[4][4];
    if (s0 == 0) {
        #pragma unroll
        for (int a = 0; a < 4; ++a)
            #pragma unroll
            for (int b = 0; b < 4; ++b) { c[a][b] = 0.f; mx[a][b] = -3.4e38f; }
    } else {
        #pragma unroll
        for (int mt = 0; mt < 4; ++mt) {
            const f32x4 cv = *(const f32x4*)(c_st  + stBase + mt * 4);
            const f32x4 mv = *(const f32x4*)(mx_st + stBase + mt * 4);
            #pragma unroll
            for (int r = 0; r < 4; ++r) { c[mt][r] = cv[r]; mx[mt][r] = mv[r]; }
        }
    }

    for (int s = s0; s < s1; ++s) {
        if (s >= ns) break;
        const int t = t0 + dt * s;
        const int sp  = s & 1;
        const int spn = sp ^ 1;

        f32x4 acc[4][4];
        #pragma unroll
        for (int a = 0; a < 4; ++a)
            #pragma unroll
            for (int b = 0; b < 4; ++b) acc[a][b] = (f32x4){0.f, 0.f, 0.f, 0.f};

        if (s > 0) {
            if (coop && tid == 0) {
                // relaxed spin (no per-poll cache ops) + ONE acquire at exit
                unsigned v;
                do {
                    v = __hip_atomic_load(&bar[rid * 32], __ATOMIC_RELAXED,
                                          __HIP_MEMORY_SCOPE_AGENT);
                    if (v < (unsigned)(4 * s)) __builtin_amdgcn_s_sleep(2);
                } while (v < (unsigned)(4 * s));
                (void)__hip_atomic_load(&bar[rid * 32], __ATOMIC_ACQUIRE,
                                        __HIP_MEMORY_SCOPE_AGENT);
            }
            __syncthreads();   // spin-result broadcast + LDS buffer-reuse fence

            // ---- stage peer h quarters (12 coherent u64 loads) ----
            const u64* srcU = hU + ((size_t)sp * 56 + rid) * 4096;
            #pragma unroll
            for (int qp = 0; qp < 4; ++qp) {
                if (coop && qp == q) continue;             // own quarter in LDS
                const int col = qp * 64 + rw * 16 + rcl;
                const int ktc = col >> 5, lqc = (col >> 3) & 3, i2c = col & 7;
                u64 vals[4];
                #pragma unroll
                for (int mt = 0; mt < 4; ++mt)
                    vals[mt] = __hip_atomic_load(srcU + (qp * 4 + mt) * 256 + tid,
                                                 __ATOMIC_RELAXED, __HIP_MEMORY_SCOPE_AGENT);
                #pragma unroll
                for (int mt = 0; mt < 4; ++mt) {
                    #pragma unroll
                    for (int rr = 0; rr < 4; ++rr) {
                        const int fi = ((ktc * 4 + mt) * 64 + rsw + rr + 16 * lqc) * 8 + i2c;
                        hh[sp][fi] = (u16)(vals[mt] >> (16 * rr));
                    }
                }
            }
            __syncthreads();

            // ---- z += h @ W^T (MFMA f16 x1) ----
            #pragma unroll
            for (int kt = 0; kt < 8; ++kt) {
                hfrag ah[4];
                #pragma unroll
                for (int mt = 0; mt < 4; ++mt)
                    ah[mt] = *(const hfrag*)&hh[sp][((kt * 4 + mt) * 64 + l) * 8];
                #pragma unroll
                for (int mt = 0; mt < 4; ++mt)
                    #pragma unroll
                    for (int g = 0; g < 4; ++g)
                        acc[mt][g] = __builtin_amdgcn_mfma_f32_16x16x32_f16(
                            ah[mt], WH[kt][g], acc[mt][g], 0, 0, 0);
            }
        }

        // ------------------ gates + state update + outputs ------------------
        u64* dstU = hU + ((size_t)spn * 56 + rid) * 4096 + q * 1024 + tid;

        #pragma unroll
        for (int mt = 0; mt < 4; ++mt) {
            f32x4 xv[4];
            #pragma unroll
            for (int g = 0; g < 4; ++g)
                xv[g] = *(const f32x4*)(xg + ((((size_t)t * 64 + g * 16 + q * 4 + w) * 4 + mt) * 64 + l) * 4);
            u64 pk = 0;
            #pragma unroll
            for (int reg = 0; reg < 4; ++reg) {
                const int row = mt * 16 + rsub + reg;
                const float zi = acc[mt][0][reg] + xv[0][reg];
                const float zf = acc[mt][1][reg] + xv[1][reg];
                const float zg = acc[mt][2][reg] + xv[2][reg];
                const float zo = acc[mt][3][reg] + xv[3][reg];
                const float c2 = sigm_(zf) * c[mt][reg] + sigm_(zi) * tanh_(zg);
                const float h2 = sigm_(zo) * tanh_(c2);
                c[mt][reg] = c2;
                const float m2 = fmaxf(mx[mt][reg], h2);
                mx[mt][reg] = m2;

                const u16 uhf = f2h_bits(h2);
                pk |= (u64)uhf << (16 * reg);

                // own-quarter LDS carry for next step (coop; harmless otherwise)
                hh[spn][((kt2 * 4 + mt) * 64 + rsub + reg + 16 * lhi) * 8 + i2] = uhf;

                if (mode == 0) {
                    if (t <= 24)
                        __builtin_nontemporal_store(m2,
                            out_pre + ((size_t)t * BB + row) * (2 * HH) + hc);
                } else if (mode == 1) {
                    if (t >= 1 && t <= 25)
                        __builtin_nontemporal_store(m2,
                            out_suf + ((size_t)(t - 1) * BB + row) * (2 * HH) + HH + hc);
                } else if (mode == 2) {
                    if (s == ns - 1)
                        __builtin_nontemporal_store(m2,
                            out_pre + ((size_t)(len - 1) * BB + row) * (2 * HH) + HH + hc);
                } else if (mode == 3) {
                    if (s == ns - 1)
                        __builtin_nontemporal_store(m2,
                            out_suf + ((size_t)(len - 1) * BB + row) * (2 * HH) + hc);
                } else {
                    // r4 in proj-A fragment layout (bf16 hi/lo): d = row*32+t
                    const int d = row * 32 + t;
                    const size_t idx = (((size_t)ktp4 * 128 + (d >> 4)) * 64
                                        + lph + (d & 15)) * 8 + ip;
                    const u16 ubh = f2bf(h2);
                    __builtin_nontemporal_store(ubh, r4Ah + idx);
                    __builtin_nontemporal_store(f2bf(h2 - bf2f(ubh)), r4Al + idx);
                }
            }
            __hip_atomic_store(dstU + mt * 256, pk,
                               __ATOMIC_RELAXED, __HIP_MEMORY_SCOPE_AGENT);
        }

        // signal end of step s (syncthreads drains all waves' stores first)
        if (coop && s + 1 < ns) {
            __syncthreads();
            if (tid == 0)
                __hip_atomic_fetch_add(&bar[rid * 32], 1u, __ATOMIC_RELEASE,
                                       __HIP_MEMORY_SCOPE_AGENT);
        }
    }

    // persist c/mx only in fallback mode (next launch reloads)
    if (!coop && s1 < TT) {
        #pragma unroll
        for (int mt = 0; mt < 4; ++mt) {
            f32x4 cv, mv;
            #pragma unroll
            for (int r = 0; r < 4; ++r) { cv[r] = c[mt][r]; mv[r] = mx[mt][r]; }
            *(f32x4*)(c_st  + stBase + mt * 4) = cv;
            *(f32x4*)(mx_st + stBase + mt * 4) = mv;
        }
    }
}

// ---------------------------------------------------------------------------
extern "C" void kernel_launch(void* const* d_in, const int* in_sizes, int n_in,
                              void* d_out, int out_size, void* d_ws, size_t ws_size,
                              hipStream_t stream)
{
    const float* x    = (const float*)d_in[0];
    const float* wif  = (const float*)d_in[1];
    const float* whf  = (const float*)d_in[2];
    const float* bf   = (const float*)d_in[3];
    const float* wib  = (const float*)d_in[4];
    const float* whb  = (const float*)d_in[5];
    const float* bb   = (const float*)d_in[6];
    const float* w2if = (const float*)d_in[7];
    const float* w2hf = (const float*)d_in[8];
    const float* b2f  = (const float*)d_in[9];
    const float* w2ib = (const float*)d_in[10];
    const float* w2hb = (const float*)d_in[11];
    const float* b2b  = (const float*)d_in[12];
    const float* wl   = (const float*)d_in[13];
    const float* bl   = (const float*)d_in[14];

    const size_t XG = (size_t)BB * TT * ZN;          // 2,097,152 floats
    float* xgfP  = (float*)d_ws;
    float* xgbP  = xgfP + XG;
    float* xg2P  = xgbP + XG;                        // 4 consecutive arrays
    float* c_st  = xg2P + 4 * XG;                    // 224*256*16 floats
    float* mx_st = c_st + (size_t)224 * 256 * 16;

    u16* p = (u16*)(mx_st + (size_t)224 * 256 * 16);
    u16* WB2h  = p; p += (size_t)2 * 262144;   // w2if, w2ib (bf16 hi/lo)
    u16* WB2l  = p; p += (size_t)2 * 262144;
    u16* WB16h = p; p += (size_t)2 * 524288;   // wif, wib
    u16* WB16l = p; p += (size_t)2 * 524288;
    u16* wlBh  = p; p += (size_t)524288;
    u16* wlBl  = p; p += (size_t)524288;
    u16* xAh   = p; p += (size_t)2048 * 512;
    u16* xAl   = p; p += (size_t)2048 * 512;
    u16* r4Ah  = p; p += (size_t)2048 * 1024;
    u16* r4Al  = p; p += (size_t)2048 * 1024;
    _Float16* W16 = (_Float16*)p; p += (size_t)4 * 262144;   // recurrence f16
    u64* hU = (u64*)(((uintptr_t)p + 15) & ~(uintptr_t)15);  // 2 x 56 x 4096 u64
    unsigned* bar = (unsigned*)(hU + (size_t)2 * 56 * 4096); // 56 x 32 (padded)

    float* outp    = (float*)d_out;
    float* out_pre = outp + (size_t)BB * TT * OO;
    float* out_suf = out_pre + (size_t)NPRE * BB * (2 * HH);

    // 0. reset per-run barrier counters (capture-safe memset node)
    hipMemsetAsync(bar, 0, (size_t)56 * 32 * sizeof(unsigned), stream);

    // 1. fragment preps
    prep_w4h<<<dim3(128, 8, 4),  256, 0, stream>>>(whf, whb, w2hf, w2hb, W16);
    prep_w2 <<<dim3(128, 8, 2),  256, 0, stream>>>(w2if, w2ib, WB2h, WB2l);
    prep_w16<<<dim3(128, 16, 2), 256, 0, stream>>>(wif, wib, WB16h, WB16l);
    prep_frag<<<dim3(64, 32),    256, 0, stream>>>(wl, ZN, wlBh, wlBl);      // T=32, K=1024
    prep_x_tmajor<<<dim3(256, 16), 256, 0, stream>>>(x, xAh, xAl);

    // 2. input-gate activation GEMMs -> fragment-layout xgP buffers (fused)
    gemm_xg<<<dim3(4, 32, 2), 256, 0, stream>>>(xAh, xAl, 0, WB16h, WB16l, 524288,
                                                bf, bb, xgfP, 16);
    gemm_xg<<<dim3(4, 32, 4), 256, 0, stream>>>(xAh, xAl, 8, WB2h, WB2l, 262144,
                                                b2f, b2b, xg2P, 8);

    // 3. recurrence: one cooperative launch (per-run barriers inside);
    //    fallback to 32 per-step launches if coop launch fails.
    {
        int cs0 = 0, cs1 = TT;
        const float* a_xgf = xgfP; const float* a_xgb = xgbP; const float* a_xg2 = xg2P;
        const _Float16* a_w16 = W16;
        u64* a_hu = hU; unsigned* a_bar = bar;
        float* a_cst = c_st; float* a_mx = mx_st;
        float* a_pre = out_pre; float* a_suf = out_suf;
        u16* a_r4h = r4Ah; u16* a_r4l = r4Al;
        void* cargs[] = { (void*)&cs0, (void*)&cs1,
                          (void*)&a_xgf, (void*)&a_xgb, (void*)&a_xg2,
                          (void*)&a_w16,
                          (void*)&a_hu, (void*)&a_bar,
                          (void*)&a_cst, (void*)&a_mx,
                          (void*)&a_pre, (void*)&a_suf,
                          (void*)&a_r4h, (void*)&a_r4l };
        hipError_t ce = hipLaunchCooperativeKernel((const void*)lstm_runs_k,
                                                   dim3(224), dim3(256), cargs, 0, stream);
        if (ce != hipSuccess) {
            for (int s = 0; s < TT; ++s)
                lstm_runs_k<<<dim3(224), dim3(256), 0, stream>>>(s, s + 1,
                    xgfP, xgbP, xg2P, W16, hU, bar, c_st, mx_st,
                    out_pre, out_suf, r4Ah, r4Al);
        }
    }

    // 4. final projection: output = r4 @ wl^T + bl  (r4 already in frag layout)
    gemm_mfma<<<dim3(2, 32), 256, 0, stream>>>(r4Ah, r4Al, 128, 0, wlBh, wlBl, 32, bl, outp, OO, 32);
}

// Round 11
// 588.541 us; speedup vs baseline: 4.4896x; 1.0853x over previous
//
#include <hip/hip_runtime.h>
#include <math.h>

#define BB 64
#define TT 32
#define II 512
#define HH 256
#define ZN 1024   // 4*H
#define OO 512
#define NPRE 25

typedef unsigned short u16;
typedef unsigned long long u64;
typedef short bfrag __attribute__((ext_vector_type(8)));      // 8 bf16 (4 VGPRs)
typedef _Float16 hfrag __attribute__((ext_vector_type(8)));   // 8 f16  (4 VGPRs)
typedef float f32x4 __attribute__((ext_vector_type(4)));

__device__ __forceinline__ float sigm_(float x) { return 1.f / (1.f + __expf(-x)); }
__device__ __forceinline__ float tanh_(float x) { return 1.f - 2.f / (__expf(2.f * x) + 1.f); }

__device__ __forceinline__ u16 f2bf(float x) {
    union { float f; unsigned u; } v; v.f = x;
    unsigned r = v.u + 0x7fffu + ((v.u >> 16) & 1u);   // RNE
    return (u16)(r >> 16);
}
__device__ __forceinline__ float bf2f(u16 b) {
    union { unsigned u; float f; } v; v.u = ((unsigned)b) << 16; return v.f;
}
__device__ __forceinline__ u16 f2h_bits(float x) {
    union { _Float16 h; u16 u; } v; v.h = (_Float16)x; return v.u;
}

// ---------------------------------------------------------------------------
// Fragment preps: fp32 [D][ld] row-major -> fragment-linear.
//   frag idx = ((kt*T + t)*64 + l)*8 + i ; d = t*16+(l&15) ; k = kt*32+((l>>4)<<3)+i
// ---------------------------------------------------------------------------
__global__ __launch_bounds__(256) void prep_frag(      // bf16 hi/lo (wl)
    const float* __restrict__ src, int ld,
    u16* __restrict__ hi, u16* __restrict__ lo)
{
    const int T  = gridDim.x >> 1;
    const int e2 = blockIdx.x * 256 + threadIdx.x;
    const int kt = blockIdx.y;
    const int i = e2 & 7, l = (e2 >> 3) & 63, t = e2 >> 9;
    const int d = t * 16 + (l & 15);
    const int k = kt * 32 + ((l >> 4) << 3) + i;
    const float v = src[(size_t)d * ld + k];
    const u16 h = f2bf(v);
    const size_t o = (size_t)kt * ((size_t)T * 512) + e2;
    hi[o] = h;
    lo[o] = f2bf(v - bf2f(h));
}

// 4 recurrence matrices [1024][256] -> f16 frag-linear (x1 scheme)
__global__ __launch_bounds__(256) void prep_w4h(
    const float* __restrict__ s0, const float* __restrict__ s1,
    const float* __restrict__ s2, const float* __restrict__ s3,
    _Float16* __restrict__ dst)
{
    const int z = blockIdx.z;
    const float* src = (z == 0) ? s0 : (z == 1) ? s1 : (z == 2) ? s2 : s3;
    const int e2 = blockIdx.x * 256 + threadIdx.x;
    const int kt = blockIdx.y;                          // 0..7
    const int i = e2 & 7, l = (e2 >> 3) & 63, t = e2 >> 9;
    const int d = t * 16 + (l & 15);
    const int k = kt * 32 + ((l >> 4) << 3) + i;
    dst[(size_t)z * 262144 + (size_t)kt * 32768 + e2] =
        (_Float16)src[(size_t)d * HH + k];
}

// 2 matrices [1024][256] bf16 hi/lo: w2if, w2ib (xg-GEMM B operands)
__global__ __launch_bounds__(256) void prep_w2(
    const float* __restrict__ s0, const float* __restrict__ s1,
    u16* __restrict__ hi, u16* __restrict__ lo)
{
    const int z = blockIdx.z;
    const float* src = z ? s1 : s0;
    const int e2 = blockIdx.x * 256 + threadIdx.x;
    const int kt = blockIdx.y;                          // 0..7
    const int i = e2 & 7, l = (e2 >> 3) & 63, t = e2 >> 9;
    const int d = t * 16 + (l & 15);
    const int k = kt * 32 + ((l >> 4) << 3) + i;
    const float v = src[(size_t)d * HH + k];
    const u16 h = f2bf(v);
    const size_t o = (size_t)z * 262144 + (size_t)kt * 32768 + e2;
    hi[o] = h;
    lo[o] = f2bf(v - bf2f(h));
}

// two [1024][512] matrices fused: wif, wib
__global__ __launch_bounds__(256) void prep_w16(
    const float* __restrict__ s0, const float* __restrict__ s1,
    u16* __restrict__ hi, u16* __restrict__ lo)
{
    const int z = blockIdx.z;
    const float* src = z ? s1 : s0;
    const int e2 = blockIdx.x * 256 + threadIdx.x;
    const int kt = blockIdx.y;                          // 0..15
    const int i = e2 & 7, l = (e2 >> 3) & 63, t = e2 >> 9;
    const int d = t * 16 + (l & 15);
    const int k = kt * 32 + ((l >> 4) << 3) + i;
    const float v = src[(size_t)d * II + k];
    const u16 h = f2bf(v);
    const size_t o = (size_t)z * 524288 + (size_t)kt * 32768 + e2;
    hi[o] = h;
    lo[o] = f2bf(v - bf2f(h));
}

// x in t-major A-frag layout: m = t*64 + row. K=512, MT=128, KT=16.
__global__ __launch_bounds__(256) void prep_x_tmajor(
    const float* __restrict__ x, u16* __restrict__ hi, u16* __restrict__ lo)
{
    const int e2 = blockIdx.x * 256 + threadIdx.x;
    const int kt = blockIdx.y;
    const int i = e2 & 7, l = (e2 >> 3) & 63, mt = e2 >> 9;
    const int d = mt * 16 + (l & 15);
    const int t = d >> 6, row = d & 63;
    const int k = kt * 32 + ((l >> 4) << 3) + i;
    const float v = x[((size_t)row * TT + t) * II + k];
    const u16 h = f2bf(v);
    const size_t o = (size_t)kt * 65536 + e2;
    hi[o] = h;
    lo[o] = f2bf(v - bf2f(h));
}

// ---------------------------------------------------------------------------
// Register-fragment MFMA GEMM (bf16 x3 ~= fp32), row-major output (tail proj).
// ---------------------------------------------------------------------------
__global__ __launch_bounds__(256) void gemm_mfma(
    const u16* __restrict__ Ahi, const u16* __restrict__ Alo, const int MT, const int kt0,
    const u16* __restrict__ Bhi, const u16* __restrict__ Blo, const int NT,
    const float* __restrict__ bias,
    float* __restrict__ C, const int ldc, const int KT)
{
    const int tid = threadIdx.x;
    const int w = tid >> 6, l = tid & 63;
    const int mt0 = blockIdx.y * 4;
    const int nt0 = blockIdx.x * 16 + w * 4;

    f32x4 acc[4][4];
    #pragma unroll
    for (int a = 0; a < 4; ++a)
        #pragma unroll
        for (int b = 0; b < 4; ++b) acc[a][b] = (f32x4){0.f, 0.f, 0.f, 0.f};

    bfrag ah0[4], al0[4], bh0[4], bl0[4];
    bfrag ah1[4], al1[4], bh1[4], bl1[4];

#define LOADF(AH, AL, BH, BL, KIDX) do {                                          \
    const int kk_ = (KIDX);                                                      \
    _Pragma("unroll") for (int mt = 0; mt < 4; ++mt) {                            \
        const size_t oa = (((size_t)(kt0 + kk_) * MT + mt0 + mt) * 64 + l) * 8;   \
        AH[mt] = *(const bfrag*)(Ahi + oa); AL[mt] = *(const bfrag*)(Alo + oa); } \
    _Pragma("unroll") for (int j = 0; j < 4; ++j) {                               \
        const size_t ob = (((size_t)kk_ * NT + nt0 + j) * 64 + l) * 8;            \
        BH[j] = *(const bfrag*)(Bhi + ob); BL[j] = *(const bfrag*)(Blo + ob); }   \
} while (0)

#define MFMAS(AH, AL, BH, BL) do {                                                \
    _Pragma("unroll") for (int mt = 0; mt < 4; ++mt)                              \
    _Pragma("unroll") for (int j = 0; j < 4; ++j) {                               \
        acc[mt][j] = __builtin_amdgcn_mfma_f32_16x16x32_bf16(AH[mt], BH[j], acc[mt][j], 0, 0, 0); \
        acc[mt][j] = __builtin_amdgcn_mfma_f32_16x16x32_bf16(AH[mt], BL[j], acc[mt][j], 0, 0, 0); \
        acc[mt][j] = __builtin_amdgcn_mfma_f32_16x16x32_bf16(AL[mt], BH[j], acc[mt][j], 0, 0, 0); } \
} while (0)

    LOADF(ah0, al0, bh0, bl0, 0);
    for (int kt = 0; kt < KT; kt += 2) {
        LOADF(ah1, al1, bh1, bl1, kt + 1);
        MFMAS(ah0, al0, bh0, bl0);
        if (kt + 2 < KT) LOADF(ah0, al0, bh0, bl0, kt + 2);
        MFMAS(ah1, al1, bh1, bl1);
    }

    const int rsub = (l >> 4) << 2;
    #pragma unroll
    for (int j = 0; j < 4; ++j) {
        const int col = (nt0 + j) * 16 + (l & 15);
        const float bv = bias[col];
        #pragma unroll
        for (int mt = 0; mt < 4; ++mt)
            #pragma unroll
            for (int reg = 0; reg < 4; ++reg)
                C[(size_t)((mt0 + mt) * 16 + rsub + reg) * ldc + col] = acc[mt][j][reg] + bv;
    }
#undef LOADF
#undef MFMAS
}

// ---------------------------------------------------------------------------
// xg-producer GEMM, z-fused (proven rounds 5-10).
// Output in MFMA C/D fragment layout: xgP[(((t*64 + nt)*4 + mt)*64 + l)*4 + reg]
// ---------------------------------------------------------------------------
__global__ __launch_bounds__(256) void gemm_xg(
    const u16* __restrict__ Ahi, const u16* __restrict__ Alo, const int kt0h,
    const u16* __restrict__ Bhi0, const u16* __restrict__ Blo0, const size_t bstride,
    const float* __restrict__ bias_even, const float* __restrict__ bias_odd,
    float* __restrict__ out0, const int KT)
{
    const int MT = 128, NT = 64;
    const int z = blockIdx.z;
    const int kt0 = (z >> 1) * kt0h;
    const u16* Bhi = Bhi0 + (size_t)(z & 1) * bstride;
    const u16* Blo = Blo0 + (size_t)(z & 1) * bstride;
    const float* bias = (z & 1) ? bias_odd : bias_even;
    float* out = out0 + (size_t)z * ((size_t)BB * TT * ZN);

    const int tid = threadIdx.x;
    const int w = tid >> 6, l = tid & 63;
    const int t = blockIdx.y;
    const int mt0 = t * 4;
    const int nt0 = blockIdx.x * 16 + w * 4;

    f32x4 acc[4][4];
    #pragma unroll
    for (int a = 0; a < 4; ++a)
        #pragma unroll
        for (int b = 0; b < 4; ++b) acc[a][b] = (f32x4){0.f, 0.f, 0.f, 0.f};

    bfrag ah0[4], al0[4], bh0[4], bl0[4];
    bfrag ah1[4], al1[4], bh1[4], bl1[4];

#define LOADF(AH, AL, BH, BL, KIDX) do {                                          \
    const int kk_ = (KIDX);                                                      \
    _Pragma("unroll") for (int mt = 0; mt < 4; ++mt) {                            \
        const size_t oa = (((size_t)(kt0 + kk_) * MT + mt0 + mt) * 64 + l) * 8;   \
        AH[mt] = *(const bfrag*)(Ahi + oa); AL[mt] = *(const bfrag*)(Alo + oa); } \
    _Pragma("unroll") for (int j = 0; j < 4; ++j) {                               \
        const size_t ob = (((size_t)kk_ * NT + nt0 + j) * 64 + l) * 8;            \
        BH[j] = *(const bfrag*)(Bhi + ob); BL[j] = *(const bfrag*)(Blo + ob); }   \
} while (0)

#define MFMAS(AH, AL, BH, BL) do {                                                \
    _Pragma("unroll") for (int mt = 0; mt < 4; ++mt)                              \
    _Pragma("unroll") for (int j = 0; j < 4; ++j) {                               \
        acc[mt][j] = __builtin_amdgcn_mfma_f32_16x16x32_bf16(AH[mt], BH[j], acc[mt][j], 0, 0, 0); \
        acc[mt][j] = __builtin_amdgcn_mfma_f32_16x16x32_bf16(AH[mt], BL[j], acc[mt][j], 0, 0, 0); \
        acc[mt][j] = __builtin_amdgcn_mfma_f32_16x16x32_bf16(AL[mt], BH[j], acc[mt][j], 0, 0, 0); } \
} while (0)

    LOADF(ah0, al0, bh0, bl0, 0);
    for (int kt = 0; kt < KT; kt += 2) {
        LOADF(ah1, al1, bh1, bl1, kt + 1);
        MFMAS(ah0, al0, bh0, bl0);
        if (kt + 2 < KT) LOADF(ah0, al0, bh0, bl0, kt + 2);
        MFMAS(ah1, al1, bh1, bl1);
    }
#undef LOADF
#undef MFMAS

    const int cl = l & 15;
    #pragma unroll
    for (int j = 0; j < 4; ++j) {
        const float bv = bias[(nt0 + j) * 16 + cl];
        #pragma unroll
        for (int mt = 0; mt < 4; ++mt) {
            f32x4 o = acc[mt][j];
            o[0] += bv; o[1] += bv; o[2] += bv; o[3] += bv;
            *(f32x4*)(out + ((((size_t)t * 64 + nt0 + j) * 4 + mt) * 64 + l) * 4) = o;
        }
    }
}

// ---------------------------------------------------------------------------
// Recurrence (round-10 structure, fence-free sync). coop: ONE cooperative
// launch; per-run 4-WG flag; h transport = u64 (4 packed f16) RELAXED AGENT
// atomics (sc-bit coherent by themselves -- rounds 6/8/10 evidence; round 4's
// failure was plain loads). Round-10 lesson: the ACQUIRE/RELEASE fences did
// whole-L2 INV/WB every step, evicting xg -> that WAS lambda. Ordering
// without fences: __syncthreads drains vmcnt(0) per wave before s_barrier,
// so all UC data stores are at the coherence point before tid0's flag add;
// reader spin-exit -> syncthreads -> UC loads cannot see flag before data.
// xg loads hoisted BEFORE the spin (latency hides under partner wait).
// h u64 slot (4096/run): idx = q*1024 + mt*256 + tid; payload = 4 regs f16.
// run ids: 0 L1 fwd full | 1 L1 bwd full | 2..26 bwd prefix len 1..25 |
//          27..51 fwd suffix len 1..25 | 52..55 L2 (r2f,r2b,r3f,r3b)
// ---------------------------------------------------------------------------
__global__ __launch_bounds__(256, 2) void lstm_runs_k(
    const int s0, const int s1,
    const float* __restrict__ xgfP, const float* __restrict__ xgbP,
    const float* __restrict__ xg2P,
    const _Float16* __restrict__ W16,
    u64* __restrict__ hU, unsigned* __restrict__ bar,
    float* __restrict__ c_st, float* __restrict__ mx_st,
    float* __restrict__ out_pre, float* __restrict__ out_suf,
    u16* __restrict__ r4Ah, u16* __restrict__ r4Al)
{
    __shared__ u16 hh[2][16384];   // 64 KB: h f16 bits, A-frag-linear, dbuf

    const int wg  = blockIdx.x;
    const int rid = wg % 56;       // co-XCD mapping: wg = q*56 + rid
    const int q   = wg / 56;
    const int tid = threadIdx.x;
    const int w   = tid >> 6;
    const int l   = tid & 63;
    const bool coop = (s1 - s0) > 1;

    const float* xg; int wmat, t0, dt, ns, mode, len = 0, part = 0;
    if (rid == 0)      { mode = 0; ns = 32; t0 = 0;  dt = 1;  xg = xgfP; wmat = 0; }
    else if (rid == 1) { mode = 1; ns = 32; t0 = 31; dt = -1; xg = xgbP; wmat = 1; }
    else if (rid < 27) { mode = 2; len = rid - 1;  ns = len;      t0 = len - 1; dt = -1; xg = xgbP; wmat = 1; }
    else if (rid < 52) { mode = 3; len = rid - 26; ns = 32 - len; t0 = len;     dt = 1;  xg = xgfP; wmat = 0; }
    else { mode = 4; part = rid - 52; ns = 32;
           xg = xg2P + (size_t)part * ((size_t)BB * TT * ZN);
           wmat = 2 + (part & 1); if (part & 1) { t0 = 31; dt = -1; } else { t0 = 0; dt = 1; } }

    if (!coop && s0 >= ns) return;

    // ---- weights -> registers (once per launch): 32 frags = 128 VGPR ----
    hfrag WH[8][4];
    {
        const _Float16* WHp = W16 + (size_t)wmat * 262144;
        #pragma unroll
        for (int kt = 0; kt < 8; ++kt)
            #pragma unroll
            for (int g = 0; g < 4; ++g) {
                const size_t ob = (((size_t)kt * 64 + g * 16 + q * 4 + w) * 64 + l) * 8;
                WH[kt][g] = *(const hfrag*)(WHp + ob);
            }
    }

    const int cl = l & 15, rsub = (l >> 4) << 2;
    const int hc = q * 64 + w * 16 + cl;                   // owned h column
    const int kt2 = hc >> 5, i2 = hc & 7, lhi = (hc >> 3) & 3;
    const size_t stBase = ((size_t)wg * 256 + tid) * 16;   // c/mx slot (fallback)
    // mode-4 r4 A-frag lane constants: k = part*256 + hc
    const int kk4 = part * 256 + hc;
    const int ktp4 = kk4 >> 5, lph = ((kk4 >> 3) & 3) * 16, ip = kk4 & 7;
    // reader decode constants (reader tid mirrors writer lane tid)
    const int rw = tid >> 6, rcl = tid & 15, rsw = ((tid >> 4) & 3) << 2;

    float c[4][4], mx[4][4];
    if (s0 == 0) {
        #pragma unroll
        for (int a = 0; a < 4; ++a)
            #pragma unroll
            for (int b = 0; b < 4; ++b) { c[a][b] = 0.f; mx[a][b] = -3.4e38f; }
    } else {
        #pragma unroll
        for (int mt = 0; mt < 4; ++mt) {
            const f32x4 cv = *(const f32x4*)(c_st  + stBase + mt * 4);
            const f32x4 mv = *(const f32x4*)(mx_st + stBase + mt * 4);
            #pragma unroll
            for (int r = 0; r < 4; ++r) { c[mt][r] = cv[r]; mx[mt][r] = mv[r]; }
        }
    }

    for (int s = s0; s < s1; ++s) {
        if (s >= ns) break;
        const int t = t0 + dt * s;
        const int sp  = s & 1;
        const int spn = sp ^ 1;

        // hoist xg loads: independent of the h exchange -> issue before the
        // spin so their latency hides under the partner wait
        f32x4 xv[4][4];
        #pragma unroll
        for (int mt = 0; mt < 4; ++mt)
            #pragma unroll
            for (int g = 0; g < 4; ++g)
                xv[mt][g] = *(const f32x4*)(xg +
                    ((((size_t)t * 64 + g * 16 + q * 4 + w) * 4 + mt) * 64 + l) * 4);

        f32x4 acc[4][4];
        #pragma unroll
        for (int a = 0; a < 4; ++a)
            #pragma unroll
            for (int b = 0; b < 4; ++b) acc[a][b] = (f32x4){0.f, 0.f, 0.f, 0.f};

        if (s > 0) {
            if (coop && tid == 0) {
                // relaxed spin: NO acquire (no L2 invalidate). Data coherence
                // comes from the UC (agent-scope atomic) data accesses.
                unsigned v;
                do {
                    v = __hip_atomic_load(&bar[rid * 32], __ATOMIC_RELAXED,
                                          __HIP_MEMORY_SCOPE_AGENT);
                    if (v < (unsigned)(4 * s)) __builtin_amdgcn_s_sleep(2);
                } while (v < (unsigned)(4 * s));
            }
            __syncthreads();   // spin-result broadcast + LDS buffer-reuse fence

            // ---- stage peer h quarters (12 coherent u64 loads) ----
            const u64* srcU = hU + ((size_t)sp * 56 + rid) * 4096;
            #pragma unroll
            for (int qp = 0; qp < 4; ++qp) {
                if (coop && qp == q) continue;             // own quarter in LDS
                const int col = qp * 64 + rw * 16 + rcl;
                const int ktc = col >> 5, lqc = (col >> 3) & 3, i2c = col & 7;
                u64 vals[4];
                #pragma unroll
                for (int mt = 0; mt < 4; ++mt)
                    vals[mt] = __hip_atomic_load(srcU + (qp * 4 + mt) * 256 + tid,
                                                 __ATOMIC_RELAXED, __HIP_MEMORY_SCOPE_AGENT);
                #pragma unroll
                for (int mt = 0; mt < 4; ++mt) {
                    #pragma unroll
                    for (int rr = 0; rr < 4; ++rr) {
                        const int fi = ((ktc * 4 + mt) * 64 + rsw + rr + 16 * lqc) * 8 + i2c;
                        hh[sp][fi] = (u16)(vals[mt] >> (16 * rr));
                    }
                }
            }
            __syncthreads();

            // ---- z += h @ W^T (MFMA f16 x1) ----
            #pragma unroll
            for (int kt = 0; kt < 8; ++kt) {
                hfrag ah[4];
                #pragma unroll
                for (int mt = 0; mt < 4; ++mt)
                    ah[mt] = *(const hfrag*)&hh[sp][((kt * 4 + mt) * 64 + l) * 8];
                #pragma unroll
                for (int mt = 0; mt < 4; ++mt)
                    #pragma unroll
                    for (int g = 0; g < 4; ++g)
                        acc[mt][g] = __builtin_amdgcn_mfma_f32_16x16x32_f16(
                            ah[mt], WH[kt][g], acc[mt][g], 0, 0, 0);
            }
        }

        // ------------------ gates + state update + outputs ------------------
        u64* dstU = hU + ((size_t)spn * 56 + rid) * 4096 + q * 1024 + tid;

        #pragma unroll
        for (int mt = 0; mt < 4; ++mt) {
            u64 pk = 0;
            #pragma unroll
            for (int reg = 0; reg < 4; ++reg) {
                const int row = mt * 16 + rsub + reg;
                const float zi = acc[mt][0][reg] + xv[mt][0][reg];
                const float zf = acc[mt][1][reg] + xv[mt][1][reg];
                const float zg = acc[mt][2][reg] + xv[mt][2][reg];
                const float zo = acc[mt][3][reg] + xv[mt][3][reg];
                const float c2 = sigm_(zf) * c[mt][reg] + sigm_(zi) * tanh_(zg);
                const float h2 = sigm_(zo) * tanh_(c2);
                c[mt][reg] = c2;
                const float m2 = fmaxf(mx[mt][reg], h2);
                mx[mt][reg] = m2;

                const u16 uhf = f2h_bits(h2);
                pk |= (u64)uhf << (16 * reg);

                // own-quarter LDS carry for next step (coop; harmless otherwise)
                hh[spn][((kt2 * 4 + mt) * 64 + rsub + reg + 16 * lhi) * 8 + i2] = uhf;

                if (mode == 0) {
                    if (t <= 24)
                        __builtin_nontemporal_store(m2,
                            out_pre + ((size_t)t * BB + row) * (2 * HH) + hc);
                } else if (mode == 1) {
                    if (t >= 1 && t <= 25)
                        __builtin_nontemporal_store(m2,
                            out_suf + ((size_t)(t - 1) * BB + row) * (2 * HH) + HH + hc);
                } else if (mode == 2) {
                    if (s == ns - 1)
                        __builtin_nontemporal_store(m2,
                            out_pre + ((size_t)(len - 1) * BB + row) * (2 * HH) + HH + hc);
                } else if (mode == 3) {
                    if (s == ns - 1)
                        __builtin_nontemporal_store(m2,
                            out_suf + ((size_t)(len - 1) * BB + row) * (2 * HH) + hc);
                } else {
                    // r4 in proj-A fragment layout (bf16 hi/lo): d = row*32+t
                    const int d = row * 32 + t;
                    const size_t idx = (((size_t)ktp4 * 128 + (d >> 4)) * 64
                                        + lph + (d & 15)) * 8 + ip;
                    const u16 ubh = f2bf(h2);
                    __builtin_nontemporal_store(ubh, r4Ah + idx);
                    __builtin_nontemporal_store(f2bf(h2 - bf2f(ubh)), r4Al + idx);
                }
            }
            __hip_atomic_store(dstU + mt * 256, pk,
                               __ATOMIC_RELAXED, __HIP_MEMORY_SCOPE_AGENT);
        }

        // signal end of step s. __syncthreads drains every wave's vmcnt(0)
        // (UC stores then at coherence point) BEFORE tid0's flag add -> no
        // release fence (no L2 writeback) needed.
        if (coop && s + 1 < ns) {
            __syncthreads();
            if (tid == 0)
                __hip_atomic_fetch_add(&bar[rid * 32], 1u, __ATOMIC_RELAXED,
                                       __HIP_MEMORY_SCOPE_AGENT);
        }
    }

    // persist c/mx only in fallback mode (next launch reloads)
    if (!coop && s1 < TT) {
        #pragma unroll
        for (int mt = 0; mt < 4; ++mt) {
            f32x4 cv, mv;
            #pragma unroll
            for (int r = 0; r < 4; ++r) { cv[r] = c[mt][r]; mv[r] = mx[mt][r]; }
            *(f32x4*)(c_st  + stBase + mt * 4) = cv;
            *(f32x4*)(mx_st + stBase + mt * 4) = mv;
        }
    }
}

// ---------------------------------------------------------------------------
extern "C" void kernel_launch(void* const* d_in, const int* in_sizes, int n_in,
                              void* d_out, int out_size, void* d_ws, size_t ws_size,
                              hipStream_t stream)
{
    const float* x    = (const float*)d_in[0];
    const float* wif  = (const float*)d_in[1];
    const float* whf  = (const float*)d_in[2];
    const float* bf   = (const float*)d_in[3];
    const float* wib  = (const float*)d_in[4];
    const float* whb  = (const float*)d_in[5];
    const float* bb   = (const float*)d_in[6];
    const float* w2if = (const float*)d_in[7];
    const float* w2hf = (const float*)d_in[8];
    const float* b2f  = (const float*)d_in[9];
    const float* w2ib = (const float*)d_in[10];
    const float* w2hb = (const float*)d_in[11];
    const float* b2b  = (const float*)d_in[12];
    const float* wl   = (const float*)d_in[13];
    const float* bl   = (const float*)d_in[14];

    const size_t XG = (size_t)BB * TT * ZN;          // 2,097,152 floats
    float* xgfP  = (float*)d_ws;
    float* xgbP  = xgfP + XG;
    float* xg2P  = xgbP + XG;                        // 4 consecutive arrays
    float* c_st  = xg2P + 4 * XG;                    // 224*256*16 floats
    float* mx_st = c_st + (size_t)224 * 256 * 16;

    u16* p = (u16*)(mx_st + (size_t)224 * 256 * 16);
    u16* WB2h  = p; p += (size_t)2 * 262144;   // w2if, w2ib (bf16 hi/lo)
    u16* WB2l  = p; p += (size_t)2 * 262144;
    u16* WB16h = p; p += (size_t)2 * 524288;   // wif, wib
    u16* WB16l = p; p += (size_t)2 * 524288;
    u16* wlBh  = p; p += (size_t)524288;
    u16* wlBl  = p; p += (size_t)524288;
    u16* xAh   = p; p += (size_t)2048 * 512;
    u16* xAl   = p; p += (size_t)2048 * 512;
    u16* r4Ah  = p; p += (size_t)2048 * 1024;
    u16* r4Al  = p; p += (size_t)2048 * 1024;
    _Float16* W16 = (_Float16*)p; p += (size_t)4 * 262144;   // recurrence f16
    u64* hU = (u64*)(((uintptr_t)p + 15) & ~(uintptr_t)15);  // 2 x 56 x 4096 u64
    unsigned* bar = (unsigned*)(hU + (size_t)2 * 56 * 4096); // 56 x 32 (padded)

    float* outp    = (float*)d_out;
    float* out_pre = outp + (size_t)BB * TT * OO;
    float* out_suf = out_pre + (size_t)NPRE * BB * (2 * HH);

    // 0. reset per-run barrier counters (capture-safe memset node)
    hipMemsetAsync(bar, 0, (size_t)56 * 32 * sizeof(unsigned), stream);

    // 1. fragment preps
    prep_w4h<<<dim3(128, 8, 4),  256, 0, stream>>>(whf, whb, w2hf, w2hb, W16);
    prep_w2 <<<dim3(128, 8, 2),  256, 0, stream>>>(w2if, w2ib, WB2h, WB2l);
    prep_w16<<<dim3(128, 16, 2), 256, 0, stream>>>(wif, wib, WB16h, WB16l);
    prep_frag<<<dim3(64, 32),    256, 0, stream>>>(wl, ZN, wlBh, wlBl);      // T=32, K=1024
    prep_x_tmajor<<<dim3(256, 16), 256, 0, stream>>>(x, xAh, xAl);

    // 2. input-gate activation GEMMs -> fragment-layout xgP buffers (fused)
    gemm_xg<<<dim3(4, 32, 2), 256, 0, stream>>>(xAh, xAl, 0, WB16h, WB16l, 524288,
                                                bf, bb, xgfP, 16);
    gemm_xg<<<dim3(4, 32, 4), 256, 0, stream>>>(xAh, xAl, 8, WB2h, WB2l, 262144,
                                                b2f, b2b, xg2P, 8);

    // 3. recurrence: one cooperative launch (per-run flags inside);
    //    fallback to 32 per-step launches if coop launch fails.
    {
        int cs0 = 0, cs1 = TT;
        const float* a_xgf = xgfP; const float* a_xgb = xgbP; const float* a_xg2 = xg2P;
        const _Float16* a_w16 = W16;
        u64* a_hu = hU; unsigned* a_bar = bar;
        float* a_cst = c_st; float* a_mx = mx_st;
        float* a_pre = out_pre; float* a_suf = out_suf;
        u16* a_r4h = r4Ah; u16* a_r4l = r4Al;
        void* cargs[] = { (void*)&cs0, (void*)&cs1,
                          (void*)&a_xgf, (void*)&a_xgb, (void*)&a_xg2,
                          (void*)&a_w16,
                          (void*)&a_hu, (void*)&a_bar,
                          (void*)&a_cst, (void*)&a_mx,
                          (void*)&a_pre, (void*)&a_suf,
                          (void*)&a_r4h, (void*)&a_r4l };
        hipError_t ce = hipLaunchCooperativeKernel((const void*)lstm_runs_k,
                                                   dim3(224), dim3(256), cargs, 0, stream);
        if (ce != hipSuccess) {
            for (int s = 0; s < TT; ++s)
                lstm_runs_k<<<dim3(224), dim3(256), 0, stream>>>(s, s + 1,
                    xgfP, xgbP, xg2P, W16, hU, bar, c_st, mx_st,
                    out_pre, out_suf, r4Ah, r4Al);
        }
    }

    // 4. final projection: output = r4 @ wl^T + bl  (r4 already in frag layout)
    gemm_mfma<<<dim3(2, 32), 256, 0, stream>>>(r4Ah, r4Al, 128, 0, wlBh, wlBl, 32, bl, outp, OO, 32);
}

// Round 12
// 523.327 us; speedup vs baseline: 5.0490x; 1.1246x over previous
//
#include <hip/hip_runtime.h>
#include <math.h>

#define BB 64
#define TT 32
#define II 512
#define HH 256
#define ZN 1024   // 4*H
#define OO 512
#define NPRE 25

typedef unsigned short u16;
typedef short bfrag __attribute__((ext_vector_type(8)));      // 8 bf16 (4 VGPRs)
typedef _Float16 hfrag __attribute__((ext_vector_type(8)));   // 8 f16  (4 VGPRs)
typedef float f32x4 __attribute__((ext_vector_type(4)));

__device__ __forceinline__ float sigm_(float x) { return 1.f / (1.f + __expf(-x)); }
__device__ __forceinline__ float tanh_(float x) { return 1.f - 2.f / (__expf(2.f * x) + 1.f); }

__device__ __forceinline__ u16 f2bf(float x) {
    union { float f; unsigned u; } v; v.f = x;
    unsigned r = v.u + 0x7fffu + ((v.u >> 16) & 1u);   // RNE
    return (u16)(r >> 16);
}
__device__ __forceinline__ float bf2f(u16 b) {
    union { unsigned u; float f; } v; v.u = ((unsigned)b) << 16; return v.f;
}
__device__ __forceinline__ u16 f2h_bits(float x) {
    union { _Float16 h; u16 u; } v; v.h = (_Float16)x; return v.u;
}

// ---------------------------------------------------------------------------
// Fragment preps: fp32 [D][ld] row-major -> fragment-linear.
//   frag idx = ((kt*T + t)*64 + l)*8 + i ; d = t*16+(l&15) ; k = kt*32+((l>>4)<<3)+i
// ---------------------------------------------------------------------------
__global__ __launch_bounds__(256) void prep_frag(      // bf16 hi/lo (wl)
    const float* __restrict__ src, int ld,
    u16* __restrict__ hi, u16* __restrict__ lo)
{
    const int T  = gridDim.x >> 1;
    const int e2 = blockIdx.x * 256 + threadIdx.x;
    const int kt = blockIdx.y;
    const int i = e2 & 7, l = (e2 >> 3) & 63, t = e2 >> 9;
    const int d = t * 16 + (l & 15);
    const int k = kt * 32 + ((l >> 4) << 3) + i;
    const float v = src[(size_t)d * ld + k];
    const u16 h = f2bf(v);
    const size_t o = (size_t)kt * ((size_t)T * 512) + e2;
    hi[o] = h;
    lo[o] = f2bf(v - bf2f(h));
}

// 4 recurrence matrices [1024][256] -> f16 frag-linear (x1 scheme)
__global__ __launch_bounds__(256) void prep_w4h(
    const float* __restrict__ s0, const float* __restrict__ s1,
    const float* __restrict__ s2, const float* __restrict__ s3,
    _Float16* __restrict__ dst)
{
    const int z = blockIdx.z;
    const float* src = (z == 0) ? s0 : (z == 1) ? s1 : (z == 2) ? s2 : s3;
    const int e2 = blockIdx.x * 256 + threadIdx.x;
    const int kt = blockIdx.y;                          // 0..7
    const int i = e2 & 7, l = (e2 >> 3) & 63, t = e2 >> 9;
    const int d = t * 16 + (l & 15);
    const int k = kt * 32 + ((l >> 4) << 3) + i;
    dst[(size_t)z * 262144 + (size_t)kt * 32768 + e2] =
        (_Float16)src[(size_t)d * HH + k];
}

// 2 matrices [1024][256] bf16 hi/lo: w2if, w2ib (xg-GEMM B operands)
__global__ __launch_bounds__(256) void prep_w2(
    const float* __restrict__ s0, const float* __restrict__ s1,
    u16* __restrict__ hi, u16* __restrict__ lo)
{
    const int z = blockIdx.z;
    const float* src = z ? s1 : s0;
    const int e2 = blockIdx.x * 256 + threadIdx.x;
    const int kt = blockIdx.y;                          // 0..7
    const int i = e2 & 7, l = (e2 >> 3) & 63, t = e2 >> 9;
    const int d = t * 16 + (l & 15);
    const int k = kt * 32 + ((l >> 4) << 3) + i;
    const float v = src[(size_t)d * HH + k];
    const u16 h = f2bf(v);
    const size_t o = (size_t)z * 262144 + (size_t)kt * 32768 + e2;
    hi[o] = h;
    lo[o] = f2bf(v - bf2f(h));
}

// two [1024][512] matrices fused: wif, wib
__global__ __launch_bounds__(256) void prep_w16(
    const float* __restrict__ s0, const float* __restrict__ s1,
    u16* __restrict__ hi, u16* __restrict__ lo)
{
    const int z = blockIdx.z;
    const float* src = z ? s1 : s0;
    const int e2 = blockIdx.x * 256 + threadIdx.x;
    const int kt = blockIdx.y;                          // 0..15
    const int i = e2 & 7, l = (e2 >> 3) & 63, t = e2 >> 9;
    const int d = t * 16 + (l & 15);
    const int k = kt * 32 + ((l >> 4) << 3) + i;
    const float v = src[(size_t)d * II + k];
    const u16 h = f2bf(v);
    const size_t o = (size_t)z * 524288 + (size_t)kt * 32768 + e2;
    hi[o] = h;
    lo[o] = f2bf(v - bf2f(h));
}

// x in t-major A-frag layout: m = t*64 + row. K=512, MT=128, KT=16.
__global__ __launch_bounds__(256) void prep_x_tmajor(
    const float* __restrict__ x, u16* __restrict__ hi, u16* __restrict__ lo)
{
    const int e2 = blockIdx.x * 256 + threadIdx.x;
    const int kt = blockIdx.y;
    const int i = e2 & 7, l = (e2 >> 3) & 63, mt = e2 >> 9;
    const int d = mt * 16 + (l & 15);
    const int t = d >> 6, row = d & 63;
    const int k = kt * 32 + ((l >> 4) << 3) + i;
    const float v = x[((size_t)row * TT + t) * II + k];
    const u16 h = f2bf(v);
    const size_t o = (size_t)kt * 65536 + e2;
    hi[o] = h;
    lo[o] = f2bf(v - bf2f(h));
}

// ---------------------------------------------------------------------------
// Register-fragment MFMA GEMM (bf16 x3 ~= fp32), row-major output (tail proj).
// ---------------------------------------------------------------------------
__global__ __launch_bounds__(256) void gemm_mfma(
    const u16* __restrict__ Ahi, const u16* __restrict__ Alo, const int MT, const int kt0,
    const u16* __restrict__ Bhi, const u16* __restrict__ Blo, const int NT,
    const float* __restrict__ bias,
    float* __restrict__ C, const int ldc, const int KT)
{
    const int tid = threadIdx.x;
    const int w = tid >> 6, l = tid & 63;
    const int mt0 = blockIdx.y * 4;
    const int nt0 = blockIdx.x * 16 + w * 4;

    f32x4 acc[4][4];
    #pragma unroll
    for (int a = 0; a < 4; ++a)
        #pragma unroll
        for (int b = 0; b < 4; ++b) acc[a][b] = (f32x4){0.f, 0.f, 0.f, 0.f};

    bfrag ah0[4], al0[4], bh0[4], bl0[4];
    bfrag ah1[4], al1[4], bh1[4], bl1[4];

#define LOADF(AH, AL, BH, BL, KIDX) do {                                          \
    const int kk_ = (KIDX);                                                      \
    _Pragma("unroll") for (int mt = 0; mt < 4; ++mt) {                            \
        const size_t oa = (((size_t)(kt0 + kk_) * MT + mt0 + mt) * 64 + l) * 8;   \
        AH[mt] = *(const bfrag*)(Ahi + oa); AL[mt] = *(const bfrag*)(Alo + oa); } \
    _Pragma("unroll") for (int j = 0; j < 4; ++j) {                               \
        const size_t ob = (((size_t)kk_ * NT + nt0 + j) * 64 + l) * 8;            \
        BH[j] = *(const bfrag*)(Bhi + ob); BL[j] = *(const bfrag*)(Blo + ob); }   \
} while (0)

#define MFMAS(AH, AL, BH, BL) do {                                                \
    _Pragma("unroll") for (int mt = 0; mt < 4; ++mt)                              \
    _Pragma("unroll") for (int j = 0; j < 4; ++j) {                               \
        acc[mt][j] = __builtin_amdgcn_mfma_f32_16x16x32_bf16(AH[mt], BH[j], acc[mt][j], 0, 0, 0); \
        acc[mt][j] = __builtin_amdgcn_mfma_f32_16x16x32_bf16(AH[mt], BL[j], acc[mt][j], 0, 0, 0); \
        acc[mt][j] = __builtin_amdgcn_mfma_f32_16x16x32_bf16(AL[mt], BH[j], acc[mt][j], 0, 0, 0); } \
} while (0)

    LOADF(ah0, al0, bh0, bl0, 0);
    for (int kt = 0; kt < KT; kt += 2) {
        LOADF(ah1, al1, bh1, bl1, kt + 1);
        MFMAS(ah0, al0, bh0, bl0);
        if (kt + 2 < KT) LOADF(ah0, al0, bh0, bl0, kt + 2);
        MFMAS(ah1, al1, bh1, bl1);
    }

    const int rsub = (l >> 4) << 2;
    #pragma unroll
    for (int j = 0; j < 4; ++j) {
        const int col = (nt0 + j) * 16 + (l & 15);
        const float bv = bias[col];
        #pragma unroll
        for (int mt = 0; mt < 4; ++mt)
            #pragma unroll
            for (int reg = 0; reg < 4; ++reg)
                C[(size_t)((mt0 + mt) * 16 + rsub + reg) * ldc + col] = acc[mt][j][reg] + bv;
    }
#undef LOADF
#undef MFMAS
}

// ---------------------------------------------------------------------------
// xg-producer GEMM, z-fused (proven rounds 5-11).
// Output in MFMA C/D fragment layout: xgP[(((t*64 + nt)*4 + mt)*64 + l)*4 + reg]
// ---------------------------------------------------------------------------
__global__ __launch_bounds__(256) void gemm_xg(
    const u16* __restrict__ Ahi, const u16* __restrict__ Alo, const int kt0h,
    const u16* __restrict__ Bhi0, const u16* __restrict__ Blo0, const size_t bstride,
    const float* __restrict__ bias_even, const float* __restrict__ bias_odd,
    float* __restrict__ out0, const int KT)
{
    const int MT = 128, NT = 64;
    const int z = blockIdx.z;
    const int kt0 = (z >> 1) * kt0h;
    const u16* Bhi = Bhi0 + (size_t)(z & 1) * bstride;
    const u16* Blo = Blo0 + (size_t)(z & 1) * bstride;
    const float* bias = (z & 1) ? bias_odd : bias_even;
    float* out = out0 + (size_t)z * ((size_t)BB * TT * ZN);

    const int tid = threadIdx.x;
    const int w = tid >> 6, l = tid & 63;
    const int t = blockIdx.y;
    const int mt0 = t * 4;
    const int nt0 = blockIdx.x * 16 + w * 4;

    f32x4 acc[4][4];
    #pragma unroll
    for (int a = 0; a < 4; ++a)
        #pragma unroll
        for (int b = 0; b < 4; ++b) acc[a][b] = (f32x4){0.f, 0.f, 0.f, 0.f};

    bfrag ah0[4], al0[4], bh0[4], bl0[4];
    bfrag ah1[4], al1[4], bh1[4], bl1[4];

#define LOADF(AH, AL, BH, BL, KIDX) do {                                          \
    const int kk_ = (KIDX);                                                      \
    _Pragma("unroll") for (int mt = 0; mt < 4; ++mt) {                            \
        const size_t oa = (((size_t)(kt0 + kk_) * MT + mt0 + mt) * 64 + l) * 8;   \
        AH[mt] = *(const bfrag*)(Ahi + oa); AL[mt] = *(const bfrag*)(Alo + oa); } \
    _Pragma("unroll") for (int j = 0; j < 4; ++j) {                               \
        const size_t ob = (((size_t)kk_ * NT + nt0 + j) * 64 + l) * 8;            \
        BH[j] = *(const bfrag*)(Bhi + ob); BL[j] = *(const bfrag*)(Blo + ob); }   \
} while (0)

#define MFMAS(AH, AL, BH, BL) do {                                                \
    _Pragma("unroll") for (int mt = 0; mt < 4; ++mt)                              \
    _Pragma("unroll") for (int j = 0; j < 4; ++j) {                               \
        acc[mt][j] = __builtin_amdgcn_mfma_f32_16x16x32_bf16(AH[mt], BH[j], acc[mt][j], 0, 0, 0); \
        acc[mt][j] = __builtin_amdgcn_mfma_f32_16x16x32_bf16(AH[mt], BL[j], acc[mt][j], 0, 0, 0); \
        acc[mt][j] = __builtin_amdgcn_mfma_f32_16x16x32_bf16(AL[mt], BH[j], acc[mt][j], 0, 0, 0); } \
} while (0)

    LOADF(ah0, al0, bh0, bl0, 0);
    for (int kt = 0; kt < KT; kt += 2) {
        LOADF(ah1, al1, bh1, bl1, kt + 1);
        MFMAS(ah0, al0, bh0, bl0);
        if (kt + 2 < KT) LOADF(ah0, al0, bh0, bl0, kt + 2);
        MFMAS(ah1, al1, bh1, bl1);
    }
#undef LOADF
#undef MFMAS

    const int cl = l & 15;
    #pragma unroll
    for (int j = 0; j < 4; ++j) {
        const float bv = bias[(nt0 + j) * 16 + cl];
        #pragma unroll
        for (int mt = 0; mt < 4; ++mt) {
            f32x4 o = acc[mt][j];
            o[0] += bv; o[1] += bv; o[2] += bv; o[3] += bv;
            *(f32x4*)(out + ((((size_t)t * 64 + nt0 + j) * 4 + mt) * 64 + l) * 4) = o;
        }
    }
}

// ---------------------------------------------------------------------------
// Recurrence, SELF-CONTAINED WGs: 224 WGs = 56 runs x 4 row-quarters, each a
// 1024-thread (16-wave) WG owning 16 batch rows x FULL 256 h-cols. Rounds
// 6-11 lesson: any cross-WG h exchange pays per-step coherence-point latency
// (atomics can't coalesce); round-9 lesson: row split must NOT stream weights.
// This shape satisfies both: full f16 weight set register-resident (16 waves x
// 128 VGPR/lane = 512 KB), h lives in LDS (8 KB dbuf), rows independent ->
// ZERO atomics / coop launch / flags; one __syncthreads per step.
// Wave w owns h-cols [w*16, w*16+16) x 4 gates: nt(g) = g*16 + w. acc[g]
// f32x4; per-thread 4 h-values (col hc = w*16 + (l&15), rows (l>>4)*4+reg).
// h LDS A-frag (M=16): read lane l' -> row l'&15, k = kt*32+(l'>>4)*8+i at
// hh[(kt*64+l')*8+i]; write h(rowl, hc): kt2=hc>>5, lane'=rowl+16*((hc>>3)&3),
// i2=hc&7. Numerics IDENTICAL to round 11 (same f16 h, fp32 gates, same xg).
// run ids: 0 L1 fwd full | 1 L1 bwd full | 2..26 bwd prefix len 1..25 |
//          27..51 fwd suffix len 1..25 | 52..55 L2 (r2f,r2b,r3f,r3b)
// ---------------------------------------------------------------------------
__global__ __launch_bounds__(1024, 1) void lstm_wg(
    const float* __restrict__ xgfP, const float* __restrict__ xgbP,
    const float* __restrict__ xg2P,
    const _Float16* __restrict__ W16,
    float* __restrict__ out_pre, float* __restrict__ out_suf,
    u16* __restrict__ r4Ah, u16* __restrict__ r4Al)
{
    __shared__ u16 hh[2][4096];   // 8 KB each: [kt 8][lane 64][i 8], f16 bits

    const int wg  = blockIdx.x;
    const int rid = wg >> 2;
    const int r   = wg & 3;        // row quarter: global rows r*16 .. r*16+15
    const int tid = threadIdx.x;
    const int w   = tid >> 6;      // wave 0..15 -> h-cols w*16 .. w*16+15
    const int l   = tid & 63;

    const float* xg; int wmat, t0, dt, ns, mode, len = 0, part = 0;
    if (rid == 0)      { mode = 0; ns = 32; t0 = 0;  dt = 1;  xg = xgfP; wmat = 0; }
    else if (rid == 1) { mode = 1; ns = 32; t0 = 31; dt = -1; xg = xgbP; wmat = 1; }
    else if (rid < 27) { mode = 2; len = rid - 1;  ns = len;      t0 = len - 1; dt = -1; xg = xgbP; wmat = 1; }
    else if (rid < 52) { mode = 3; len = rid - 26; ns = 32 - len; t0 = len;     dt = 1;  xg = xgfP; wmat = 0; }
    else { mode = 4; part = rid - 52; ns = 32;
           xg = xg2P + (size_t)part * ((size_t)BB * TT * ZN);
           wmat = 2 + (part & 1); if (part & 1) { t0 = 31; dt = -1; } else { t0 = 0; dt = 1; } }

    // ---- weights -> registers (once): 32 frags = 128 VGPR/lane ----
    hfrag WH[8][4];
    {
        const _Float16* WHp = W16 + (size_t)wmat * 262144;
        #pragma unroll
        for (int kt = 0; kt < 8; ++kt)
            #pragma unroll
            for (int g = 0; g < 4; ++g) {
                const size_t ob = (((size_t)kt * 64 + g * 16 + w) * 64 + l) * 8;
                WH[kt][g] = *(const hfrag*)(WHp + ob);
            }
    }

    const int cl  = l & 15;
    const int lr4 = (l >> 4) << 2;           // local row sub-offset 0,4,8,12
    const int hc  = w * 16 + cl;             // owned h column
    const int kt2 = hc >> 5, i2 = hc & 7, lq = (hc >> 3) & 3;
    // mode-4 r4 proj-A frag constants: k = part*256 + hc
    const int kk4 = part * 256 + hc;
    const int ktp4 = kk4 >> 5, lph = ((kk4 >> 3) & 3) * 16, ip = kk4 & 7;

    float c[4], mx[4];
    #pragma unroll
    for (int e = 0; e < 4; ++e) { c[e] = 0.f; mx[e] = -3.4e38f; }

    for (int s = 0; s < ns; ++s) {
        const int t = t0 + dt * s;
        const int sp  = s & 1;
        const int spn = sp ^ 1;

        // xg fragment loads (independent of h -> scheduler hides under MFMA)
        f32x4 xv[4];
        #pragma unroll
        for (int g = 0; g < 4; ++g)
            xv[g] = *(const f32x4*)(xg +
                ((((size_t)t * 64 + g * 16 + w) * 4 + r) * 64 + l) * 4);

        f32x4 acc[4];
        #pragma unroll
        for (int g = 0; g < 4; ++g) acc[g] = (f32x4){0.f, 0.f, 0.f, 0.f};

        if (s > 0) {
            // z += h @ W^T (MFMA f16 x1); A-frags broadcast from LDS
            #pragma unroll
            for (int kt = 0; kt < 8; ++kt) {
                const hfrag ah = *(const hfrag*)&hh[sp][(kt * 64 + l) * 8];
                #pragma unroll
                for (int g = 0; g < 4; ++g)
                    acc[g] = __builtin_amdgcn_mfma_f32_16x16x32_f16(
                        ah, WH[kt][g], acc[g], 0, 0, 0);
            }
        }

        // ------------------ gates + state update + outputs ------------------
        #pragma unroll
        for (int reg = 0; reg < 4; ++reg) {
            const int rowl = lr4 + reg;          // local row 0..15
            const int row  = r * 16 + rowl;      // global batch row
            const float zi = acc[0][reg] + xv[0][reg];
            const float zf = acc[1][reg] + xv[1][reg];
            const float zg = acc[2][reg] + xv[2][reg];
            const float zo = acc[3][reg] + xv[3][reg];
            const float c2 = sigm_(zf) * c[reg] + sigm_(zi) * tanh_(zg);
            const float h2 = sigm_(zo) * tanh_(c2);
            c[reg] = c2;
            const float m2 = fmaxf(mx[reg], h2);
            mx[reg] = m2;

            // h -> LDS A-frag for next step
            const u16 uhf = f2h_bits(h2);
            hh[spn][(kt2 * 64 + rowl + 16 * lq) * 8 + i2] = uhf;

            if (mode == 0) {
                if (t <= 24)
                    __builtin_nontemporal_store(m2,
                        out_pre + ((size_t)t * BB + row) * (2 * HH) + hc);
            } else if (mode == 1) {
                if (t >= 1 && t <= 25)
                    __builtin_nontemporal_store(m2,
                        out_suf + ((size_t)(t - 1) * BB + row) * (2 * HH) + HH + hc);
            } else if (mode == 2) {
                if (s == ns - 1)
                    __builtin_nontemporal_store(m2,
                        out_pre + ((size_t)(len - 1) * BB + row) * (2 * HH) + HH + hc);
            } else if (mode == 3) {
                if (s == ns - 1)
                    __builtin_nontemporal_store(m2,
                        out_suf + ((size_t)(len - 1) * BB + row) * (2 * HH) + hc);
            } else {
                // r4 in proj-A fragment layout (bf16 hi/lo): d = row*32 + t
                const int d = row * 32 + t;
                const size_t idx = (((size_t)ktp4 * 128 + (d >> 4)) * 64
                                    + lph + (d & 15)) * 8 + ip;
                const u16 ubh = f2bf(h2);
                __builtin_nontemporal_store(ubh, r4Ah + idx);
                __builtin_nontemporal_store(f2bf(h2 - bf2f(ubh)), r4Al + idx);
            }
        }

        // writes to hh[spn] visible before step s+1 reads them; also fences
        // the buffer swap (hh[sp] reads above completed before its reuse)
        __syncthreads();
    }
}

// ---------------------------------------------------------------------------
extern "C" void kernel_launch(void* const* d_in, const int* in_sizes, int n_in,
                              void* d_out, int out_size, void* d_ws, size_t ws_size,
                              hipStream_t stream)
{
    const float* x    = (const float*)d_in[0];
    const float* wif  = (const float*)d_in[1];
    const float* whf  = (const float*)d_in[2];
    const float* bf   = (const float*)d_in[3];
    const float* wib  = (const float*)d_in[4];
    const float* whb  = (const float*)d_in[5];
    const float* bb   = (const float*)d_in[6];
    const float* w2if = (const float*)d_in[7];
    const float* w2hf = (const float*)d_in[8];
    const float* b2f  = (const float*)d_in[9];
    const float* w2ib = (const float*)d_in[10];
    const float* w2hb = (const float*)d_in[11];
    const float* b2b  = (const float*)d_in[12];
    const float* wl   = (const float*)d_in[13];
    const float* bl   = (const float*)d_in[14];

    const size_t XG = (size_t)BB * TT * ZN;          // 2,097,152 floats
    float* xgfP  = (float*)d_ws;
    float* xgbP  = xgfP + XG;
    float* xg2P  = xgbP + XG;                        // 4 consecutive arrays

    u16* p = (u16*)(xg2P + 4 * XG);
    u16* WB2h  = p; p += (size_t)2 * 262144;   // w2if, w2ib (bf16 hi/lo)
    u16* WB2l  = p; p += (size_t)2 * 262144;
    u16* WB16h = p; p += (size_t)2 * 524288;   // wif, wib
    u16* WB16l = p; p += (size_t)2 * 524288;
    u16* wlBh  = p; p += (size_t)524288;
    u16* wlBl  = p; p += (size_t)524288;
    u16* xAh   = p; p += (size_t)2048 * 512;
    u16* xAl   = p; p += (size_t)2048 * 512;
    u16* r4Ah  = p; p += (size_t)2048 * 1024;
    u16* r4Al  = p; p += (size_t)2048 * 1024;
    _Float16* W16 = (_Float16*)p;                    // recurrence f16 (4 mats)

    float* outp    = (float*)d_out;
    float* out_pre = outp + (size_t)BB * TT * OO;
    float* out_suf = out_pre + (size_t)NPRE * BB * (2 * HH);

    // 1. fragment preps
    prep_w4h<<<dim3(128, 8, 4),  256, 0, stream>>>(whf, whb, w2hf, w2hb, W16);
    prep_w2 <<<dim3(128, 8, 2),  256, 0, stream>>>(w2if, w2ib, WB2h, WB2l);
    prep_w16<<<dim3(128, 16, 2), 256, 0, stream>>>(wif, wib, WB16h, WB16l);
    prep_frag<<<dim3(64, 32),    256, 0, stream>>>(wl, ZN, wlBh, wlBl);      // T=32, K=1024
    prep_x_tmajor<<<dim3(256, 16), 256, 0, stream>>>(x, xAh, xAl);

    // 2. input-gate activation GEMMs -> fragment-layout xgP buffers (fused)
    gemm_xg<<<dim3(4, 32, 2), 256, 0, stream>>>(xAh, xAl, 0, WB16h, WB16l, 524288,
                                                bf, bb, xgfP, 16);
    gemm_xg<<<dim3(4, 32, 4), 256, 0, stream>>>(xAh, xAl, 8, WB2h, WB2l, 262144,
                                                b2f, b2b, xg2P, 8);

    // 3. recurrence: 224 self-contained WGs (56 runs x 4 row-quarters),
    //    1024 threads each, weights in VGPRs, h in LDS. Plain launch.
    lstm_wg<<<dim3(224), dim3(1024), 0, stream>>>(xgfP, xgbP, xg2P, W16,
                                                  out_pre, out_suf, r4Ah, r4Al);

    // 4. final projection: output = r4 @ wl^T + bl  (r4 already in frag layout)
    gemm_mfma<<<dim3(2, 32), 256, 0, stream>>>(r4Ah, r4Al, 128, 0, wlBh, wlBl, 32, bl, outp, OO, 32);
}